// Round 1
// baseline (347.396 us; speedup 1.0000x reference)
//
#include <hip/hip_runtime.h>
#include <stdint.h>

#define BATCH 32
#define NANCH 8400
#define NCLS 80
#define KPRE 1000
#define KPAD 1024
#define MAXDET 100
#define CONF 0.2f
#define IOUTHR 0.7f

typedef unsigned long long ull;

// monotonic map: float -> uint32 preserving total order
__device__ __forceinline__ uint32_t fmap(float f) {
  uint32_t u = __float_as_uint(f);
  return (u & 0x80000000u) ? ~u : (u | 0x80000000u);
}

// ---------------- Kernel 1: decode (DFL + class max/argmax + box) ----------------
__global__ __launch_bounds__(256) void k_decode(
    const float* __restrict__ pboxes,   // [B][N][64]
    const float* __restrict__ pcls,     // [B][N][80]
    float* __restrict__ g_scores,       // [B][N]
    float4* __restrict__ g_boxes,       // [B][N]
    int* __restrict__ g_cls)            // [B][N]
{
  int gid = blockIdx.x * blockDim.x + threadIdx.x;
  if (gid >= BATCH * NANCH) return;
  int n = gid % NANCH;

  // class max / argmax (first occurrence wins: strict >)
  const float4* pc = (const float4*)(pcls + (size_t)gid * NCLS);
  float best = -3.402823466e38f;
  int bidx = 0;
  #pragma unroll
  for (int k = 0; k < NCLS / 4; ++k) {
    float4 v = pc[k];
    if (v.x > best) { best = v.x; bidx = 4 * k + 0; }
    if (v.y > best) { best = v.y; bidx = 4 * k + 1; }
    if (v.z > best) { best = v.z; bidx = 4 * k + 2; }
    if (v.w > best) { best = v.w; bidx = 4 * k + 3; }
  }

  // DFL: softmax over 16 then dot with arange(16), matching JAX order
  const float4* pb = (const float4*)(pboxes + (size_t)gid * 64);
  float dist[4];
  #pragma unroll
  for (int k = 0; k < 4; ++k) {
    float v[16];
    #pragma unroll
    for (int q = 0; q < 4; ++q) {
      float4 t = pb[k * 4 + q];
      v[q * 4 + 0] = t.x; v[q * 4 + 1] = t.y; v[q * 4 + 2] = t.z; v[q * 4 + 3] = t.w;
    }
    float m = v[0];
    #pragma unroll
    for (int r = 1; r < 16; ++r) m = fmaxf(m, v[r]);
    float e[16];
    float s = 0.f;
    #pragma unroll
    for (int r = 0; r < 16; ++r) { e[r] = expf(v[r] - m); s += e[r]; }
    float acc = 0.f;
    #pragma unroll
    for (int r = 0; r < 16; ++r) acc += (e[r] / s) * (float)r;
    dist[k] = acc;
  }

  // anchors: levels 80x80(s8), 40x40(s16), 20x20(s32); anchor=(col+0.5, row+0.5)
  int n0, W; float sf;
  if (n < 6400)      { n0 = n;        W = 80; sf = 8.f;  }
  else if (n < 8000) { n0 = n - 6400; W = 40; sf = 16.f; }
  else               { n0 = n - 8000; W = 20; sf = 32.f; }
  float ax = (float)(n0 % W) + 0.5f;
  float ay = (float)(n0 / W) + 0.5f;

  float4 bx;
  bx.x = (ax - dist[0]) * sf;
  bx.y = (ay - dist[1]) * sf;
  bx.z = (ax + dist[2]) * sf;
  bx.w = (ay + dist[3]) * sf;

  g_boxes[gid] = bx;
  g_scores[gid] = best;
  g_cls[gid] = bidx;
}

// ---------------- Kernel 2: exact stable top-1000 per batch ----------------
__global__ __launch_bounds__(1024) void k_topk(
    const float* __restrict__ g_scores,
    const float4* __restrict__ g_boxes,
    const int* __restrict__ g_cls,
    const float* __restrict__ g_dist_in,   // [B][N][1]
    float* __restrict__ g_tscore,          // [B][KPAD]
    float4* __restrict__ g_tbox,           // [B][KPAD]
    int* __restrict__ g_tcls,              // [B][KPAD]
    float* __restrict__ g_tdist)           // [B][KPAD]
{
  int b = blockIdx.x;
  int tid = threadIdx.x;
  int lane = tid & 63;
  __shared__ float ls[NANCH];
  __shared__ ull skeys[KPAD];
  __shared__ int s_cnt;
  __shared__ int s_pos;

  const float* sc = g_scores + (size_t)b * NANCH;
  for (int i = tid; i < NANCH; i += 1024) ls[i] = sc[i];
  __syncthreads();

  // bisection for exact 1000th-largest composite key (all keys distinct)
  ull lo = 0, hi = ~0ull;
  while (hi - lo > 1) {
    ull mid = lo + ((hi - lo) >> 1);
    if (tid == 0) s_cnt = 0;
    __syncthreads();
    int local = 0;
    for (int i = tid; i < NANCH; i += 1024) {
      ull key = ((ull)fmap(ls[i]) << 32) | (ull)(uint32_t)(NANCH - 1 - i);
      local += (key >= mid) ? 1 : 0;
    }
    #pragma unroll
    for (int off = 32; off > 0; off >>= 1) local += __shfl_down(local, off);
    if (lane == 0) atomicAdd(&s_cnt, local);
    __syncthreads();
    int cnt = s_cnt;
    __syncthreads();
    if (cnt >= KPRE) lo = mid; else hi = mid;
  }
  // lo == exact 1000th largest key; exactly KPRE keys >= lo

  if (tid == 0) s_pos = 0;
  __syncthreads();
  for (int i = tid; i < NANCH; i += 1024) {
    ull key = ((ull)fmap(ls[i]) << 32) | (ull)(uint32_t)(NANCH - 1 - i);
    bool sel = (key >= lo);
    ull m = __ballot(sel);
    int base = 0;
    if (lane == 0) base = atomicAdd(&s_pos, __popcll(m));
    base = __shfl(base, 0);
    if (sel) skeys[base + __popcll(m & ((1ull << lane) - 1ull))] = key;
  }
  if (tid >= KPRE) skeys[tid] = 0ull;  // pad sorts last (real keys have bit63 set)
  __syncthreads();

  // bitonic sort 1024 keys, descending
  for (int k = 2; k <= KPAD; k <<= 1) {
    for (int j = k >> 1; j > 0; j >>= 1) {
      int i = tid;
      int ixj = i ^ j;
      if (ixj > i) {
        ull a = skeys[i], c = skeys[ixj];
        bool descDir = ((i & k) == 0);
        bool doSwap = descDir ? (a < c) : (a > c);
        if (doSwap) { skeys[i] = c; skeys[ixj] = a; }
      }
      __syncthreads();
    }
  }

  if (tid < KPRE) {
    ull key = skeys[tid];
    int n = (NANCH - 1) - (int)(uint32_t)(key & 0xffffffffu);
    size_t src = (size_t)b * NANCH + n;
    size_t dst = (size_t)b * KPAD + tid;
    g_tscore[dst] = ls[n];
    g_tbox[dst] = g_boxes[src];
    g_tcls[dst] = g_cls[src];
    g_tdist[dst] = g_dist_in[src];
  }
}

// ---------------- Kernel 3: suppression bit-matrix ----------------
__global__ __launch_bounds__(256) void k_iou(
    const float4* __restrict__ g_tbox,
    ull* __restrict__ g_sup)              // [B][KPAD][16]
{
  int b = blockIdx.x;
  int i = blockIdx.y * 256 + threadIdx.x;
  __shared__ float4 s_box[KPRE];
  __shared__ float s_area[KPRE];
  for (int t = threadIdx.x; t < KPRE; t += 256) {
    float4 v = g_tbox[(size_t)b * KPAD + t];
    s_box[t] = v;
    s_area[t] = (v.z - v.x) * (v.w - v.y);
  }
  __syncthreads();
  if (i >= KPRE) return;

  float4 bi = s_box[i];
  float ai = s_area[i];
  ull* out = g_sup + ((size_t)b * KPAD + i) * 16;
  for (int w = 0; w < 16; ++w) {
    ull bits = 0;
    int j0 = w * 64;
    int jend = min(j0 + 64, KPRE);
    int jstart = max(j0, i + 1);
    for (int j = jstart; j < jend; ++j) {
      float4 bj = s_box[j];
      float ltx = fmaxf(bi.x, bj.x);
      float lty = fmaxf(bi.y, bj.y);
      float rbx = fminf(bi.z, bj.z);
      float rby = fminf(bi.w, bj.w);
      float wx = fmaxf(rbx - ltx, 0.f);
      float wy = fmaxf(rby - lty, 0.f);
      float inter = wx * wy;
      float den = ((ai + s_area[j]) - inter) + 1e-7f;
      float iou = inter / den;
      if (iou > IOUTHR) bits |= (1ull << (j - j0));
    }
    out[w] = bits;
  }
}

// ---------------- Kernel 4: sequential NMS + final selection + output ----------------
__global__ __launch_bounds__(64) void k_nms(
    const ull* __restrict__ g_sup,
    const float* __restrict__ g_tscore,
    const float4* __restrict__ g_tbox,
    const int* __restrict__ g_tcls,
    const float* __restrict__ g_tdist,
    float* __restrict__ out)
{
  int b = blockIdx.x;
  int lane = threadIdx.x;
  __shared__ ull rowbuf[64][16];
  __shared__ float s_score[KPAD];
  __shared__ ull s_removedw[16];
  __shared__ ull s_valid[16];
  __shared__ int s_sel[MAXDET];
  __shared__ int s_flag[MAXDET];

  for (int t = lane; t < KPAD; t += 64)
    s_score[t] = g_tscore[(size_t)b * KPAD + t];

  ull rem = 0;  // lane w (mod 16) mirrors removed word w
  const ull* sup = g_sup + (size_t)b * KPAD * 16;
  for (int chunk = 0; chunk < 16; ++chunk) {
    int c0 = chunk * 64;
    __syncthreads();
    for (int t = lane; t < 64 * 16; t += 64)
      rowbuf[t >> 4][t & 15] = sup[(size_t)(c0 + (t >> 4)) * 16 + (t & 15)];
    __syncthreads();
    int imax = min(64, KPRE - c0);
    for (int ii = 0; ii < imax; ++ii) {
      ull remw = __shfl(rem, chunk);          // word containing bit for i=c0+ii
      bool kept = !((remw >> ii) & 1ull);
      if (kept) rem |= rowbuf[ii][lane & 15];
    }
  }
  if (lane < 16) s_removedw[lane] = rem;
  __syncthreads();

  // valid mask: kept && score > CONF
  for (int k = 0; k < 16; ++k) {
    int c = k * 64 + lane;
    bool v = (c < KPRE) && (s_score[c] > CONF) && !((s_removedw[k] >> lane) & 1ull);
    ull m = __ballot(v);
    if (lane == 0) s_valid[k] = m;
  }
  __syncthreads();

  // second top_k on masked scores: valid entries in array order, then
  // invalid entries (all tied at -1.0) in array order
  if (lane == 0) {
    int cnt = 0;
    for (int i = 0; i < KPRE && cnt < MAXDET; ++i)
      if ((s_valid[i >> 6] >> (i & 63)) & 1ull) { s_sel[cnt] = i; s_flag[cnt] = 1; ++cnt; }
    for (int i = 0; i < KPRE && cnt < MAXDET; ++i)
      if (!((s_valid[i >> 6] >> (i & 63)) & 1ull)) { s_sel[cnt] = i; s_flag[cnt] = 0; ++cnt; }
  }
  __syncthreads();

  float* obox = out;                                 // [B][100][4]
  float* osc  = out + (size_t)BATCH * MAXDET * 4;    // [B][100]
  float* ocls = out + (size_t)BATCH * MAXDET * 5;    // [B][100]
  float* odst = out + (size_t)BATCH * MAXDET * 6;    // [B][100][1]
  float* oval = out + (size_t)BATCH * MAXDET * 7;    // [B][100]

  for (int s = lane; s < MAXDET; s += 64) {
    int i = s_sel[s];
    int fl = s_flag[s];
    size_t src = (size_t)b * KPAD + i;
    float4 bx = g_tbox[src];
    float scv = fl ? s_score[i] : -1.0f;
    float clv = (float)g_tcls[src];
    float ddv = g_tdist[src];
    size_t o = (size_t)b * MAXDET + s;
    obox[o * 4 + 0] = bx.x;
    obox[o * 4 + 1] = bx.y;
    obox[o * 4 + 2] = bx.z;
    obox[o * 4 + 3] = bx.w;
    osc[o] = scv;
    ocls[o] = clv;
    odst[o] = ddv;
    oval[o] = fl ? 1.0f : 0.0f;
  }
}

extern "C" void kernel_launch(void* const* d_in, const int* in_sizes, int n_in,
                              void* d_out, int out_size, void* d_ws, size_t ws_size,
                              hipStream_t stream) {
  const float* pboxes = (const float*)d_in[0];   // (32,8400,64)
  const float* pcls   = (const float*)d_in[1];   // (32,8400,80)
  const float* pdist  = (const float*)d_in[2];   // (32,8400,1)
  // d_in[3] = images, unused by the reference computation
  float* out = (float*)d_out;

  char* ws = (char*)d_ws;
  size_t nBN = (size_t)BATCH * NANCH;
  size_t off = 0;
  float*  g_scores = (float*)(ws + off);  off += nBN * 4;                 // 1,075,200
  float4* g_boxes  = (float4*)(ws + off); off += nBN * 16;                // 4,300,800
  int*    g_cls    = (int*)(ws + off);    off += nBN * 4;                 // 1,075,200
  float*  g_tscore = (float*)(ws + off);  off += (size_t)BATCH * KPAD * 4;
  float4* g_tbox   = (float4*)(ws + off); off += (size_t)BATCH * KPAD * 16;
  int*    g_tcls   = (int*)(ws + off);    off += (size_t)BATCH * KPAD * 4;
  float*  g_tdist  = (float*)(ws + off);  off += (size_t)BATCH * KPAD * 4;
  ull*    g_sup    = (ull*)(ws + off);    off += (size_t)BATCH * KPAD * 16 * 8;
  // total ~12.5 MB of d_ws

  int total = BATCH * NANCH;
  k_decode<<<(total + 255) / 256, 256, 0, stream>>>(pboxes, pcls, g_scores, g_boxes, g_cls);
  k_topk<<<BATCH, 1024, 0, stream>>>(g_scores, g_boxes, g_cls, pdist,
                                     g_tscore, g_tbox, g_tcls, g_tdist);
  dim3 giou(BATCH, 4);
  k_iou<<<giou, 256, 0, stream>>>(g_tbox, g_sup);
  k_nms<<<BATCH, 64, 0, stream>>>(g_sup, g_tscore, g_tbox, g_tcls, g_tdist, out);
}

// Round 2
// 237.144 us; speedup vs baseline: 1.4649x; 1.4649x over previous
//
#include <hip/hip_runtime.h>
#include <stdint.h>

#define BATCH 32
#define NANCH 8400
#define NCLS 80
#define KPRE 1000
#define KPAD 1024
#define MAXDET 100
#define CONF 0.2f
#define IOUTHR 0.7f

typedef unsigned long long ull;

// monotonic map: float -> uint32 preserving total order
__device__ __forceinline__ uint32_t fmap(float f) {
  uint32_t u = __float_as_uint(f);
  return (u & 0x80000000u) ? ~u : (u | 0x80000000u);
}

// ---------------- Kernel 1: decode (DFL + class max/argmax + box) ----------------
__global__ __launch_bounds__(256) void k_decode(
    const float* __restrict__ pboxes,   // [B][N][64]
    const float* __restrict__ pcls,     // [B][N][80]
    float* __restrict__ g_scores,       // [B][N]
    float4* __restrict__ g_boxes,       // [B][N]
    int* __restrict__ g_cls)            // [B][N]
{
  int gid = blockIdx.x * blockDim.x + threadIdx.x;
  if (gid >= BATCH * NANCH) return;
  int n = gid % NANCH;

  // class max / argmax (first occurrence wins: strict >)
  const float4* pc = (const float4*)(pcls + (size_t)gid * NCLS);
  float best = -3.402823466e38f;
  int bidx = 0;
  #pragma unroll
  for (int k = 0; k < NCLS / 4; ++k) {
    float4 v = pc[k];
    if (v.x > best) { best = v.x; bidx = 4 * k + 0; }
    if (v.y > best) { best = v.y; bidx = 4 * k + 1; }
    if (v.z > best) { best = v.z; bidx = 4 * k + 2; }
    if (v.w > best) { best = v.w; bidx = 4 * k + 3; }
  }

  // DFL: softmax over 16 then dot with arange(16), matching JAX order
  const float4* pb = (const float4*)(pboxes + (size_t)gid * 64);
  float dist[4];
  #pragma unroll
  for (int k = 0; k < 4; ++k) {
    float v[16];
    #pragma unroll
    for (int q = 0; q < 4; ++q) {
      float4 t = pb[k * 4 + q];
      v[q * 4 + 0] = t.x; v[q * 4 + 1] = t.y; v[q * 4 + 2] = t.z; v[q * 4 + 3] = t.w;
    }
    float m = v[0];
    #pragma unroll
    for (int r = 1; r < 16; ++r) m = fmaxf(m, v[r]);
    float e[16];
    float s = 0.f;
    #pragma unroll
    for (int r = 0; r < 16; ++r) { e[r] = expf(v[r] - m); s += e[r]; }
    float acc = 0.f;
    #pragma unroll
    for (int r = 0; r < 16; ++r) acc += (e[r] / s) * (float)r;
    dist[k] = acc;
  }

  // anchors: levels 80x80(s8), 40x40(s16), 20x20(s32); anchor=(col+0.5, row+0.5)
  int n0, W; float sf;
  if (n < 6400)      { n0 = n;        W = 80; sf = 8.f;  }
  else if (n < 8000) { n0 = n - 6400; W = 40; sf = 16.f; }
  else               { n0 = n - 8000; W = 20; sf = 32.f; }
  float ax = (float)(n0 % W) + 0.5f;
  float ay = (float)(n0 / W) + 0.5f;

  float4 bx;
  bx.x = (ax - dist[0]) * sf;
  bx.y = (ay - dist[1]) * sf;
  bx.z = (ax + dist[2]) * sf;
  bx.w = (ay + dist[3]) * sf;

  g_boxes[gid] = bx;
  g_scores[gid] = best;
  g_cls[gid] = bidx;
}

// ---------------- Kernel 2: exact stable top-1000 per batch ----------------
// composite 46-bit key: (fmap(score) << 14) | (NANCH-1-i). All keys distinct.
#define KBITS 46
#define NITER 46
#define NQ 9   // ceil(8400/1024)

__global__ __launch_bounds__(1024) void k_topk(
    const float* __restrict__ g_scores,
    const float4* __restrict__ g_boxes,
    const int* __restrict__ g_cls,
    const float* __restrict__ g_dist_in,   // [B][N][1]
    float* __restrict__ g_tscore,          // [B][KPAD]
    float4* __restrict__ g_tbox,           // [B][KPAD]
    int* __restrict__ g_tcls,              // [B][KPAD]
    float* __restrict__ g_tdist)           // [B][KPAD]
{
  int b = blockIdx.x;
  int tid = threadIdx.x;
  int lane = tid & 63;
  __shared__ float ls[NANCH];
  __shared__ ull skeys[KPAD];
  __shared__ int s_cnt[NITER];
  __shared__ int s_pos;

  const float* sc = g_scores + (size_t)b * NANCH;

  // load scores to LDS + build per-thread keys in registers (static indexing)
  ull key[NQ];
  #pragma unroll
  for (int q = 0; q < NQ; ++q) {
    int i = tid + q * 1024;
    if (i < NANCH) {
      float x = sc[i];
      ls[i] = x;
      key[q] = ((ull)fmap(x) << 14) | (ull)(uint32_t)(NANCH - 1 - i);
    } else {
      key[q] = 0ull;  // never selected (mid >= 1 always; real keys > 0)
    }
  }
  if (tid < NITER) s_cnt[tid] = 0;
  if (tid == 0) s_pos = 0;
  __syncthreads();

  // bisection for exact 1000th-largest key: 46 rounds, 1 barrier each
  ull lo = 0, hi = 1ull << KBITS;
  for (int it = 0; it < NITER; ++it) {
    ull mid = lo + ((hi - lo) >> 1);
    int local = 0;
    #pragma unroll
    for (int q = 0; q < NQ; ++q) local += (key[q] >= mid) ? 1 : 0;
    #pragma unroll
    for (int off = 32; off > 0; off >>= 1) local += __shfl_down(local, off);
    if (lane == 0) atomicAdd(&s_cnt[it], local);
    __syncthreads();
    int cnt = s_cnt[it];
    if (cnt >= KPRE) lo = mid; else hi = mid;
  }
  // lo == exact 1000th largest key; exactly KPRE keys >= lo

  // compact selected keys to LDS
  #pragma unroll
  for (int q = 0; q < NQ; ++q) {
    bool sel = (key[q] >= lo);
    ull m = __ballot(sel);
    int base = 0;
    if (lane == 0) base = atomicAdd(&s_pos, __popcll(m));
    base = __shfl(base, 0);
    if (sel) skeys[base + __popcll(m & ((1ull << lane) - 1ull))] = key[q];
  }
  if (tid >= KPRE) skeys[tid] = 0ull;  // pad sorts last
  __syncthreads();

  // bitonic sort 1024 keys, descending
  for (int k = 2; k <= KPAD; k <<= 1) {
    for (int j = k >> 1; j > 0; j >>= 1) {
      int i = tid;
      int ixj = i ^ j;
      if (ixj > i) {
        ull a = skeys[i], c = skeys[ixj];
        bool descDir = ((i & k) == 0);
        bool doSwap = descDir ? (a < c) : (a > c);
        if (doSwap) { skeys[i] = c; skeys[ixj] = a; }
      }
      __syncthreads();
    }
  }

  if (tid < KPRE) {
    ull kk = skeys[tid];
    int n = (NANCH - 1) - (int)(uint32_t)(kk & 0x3FFFull);
    size_t src = (size_t)b * NANCH + n;
    size_t dst = (size_t)b * KPAD + tid;
    g_tscore[dst] = ls[n];
    g_tbox[dst] = g_boxes[src];
    g_tcls[dst] = g_cls[src];
    g_tdist[dst] = g_dist_in[src];
  }
}

// ---------------- Kernel 3: suppression bit-matrix (1 word per wave-task) ----------------
__global__ __launch_bounds__(256) void k_iou(
    const float4* __restrict__ g_tbox,
    ull* __restrict__ g_sup)              // [B][KPAD][16]
{
  int b = blockIdx.x;
  int c = blockIdx.y;            // row-chunk: rows [c*64, c*64+64)
  int tid = threadIdx.x;
  int wave = tid >> 6;           // 4 waves/block
  int lane = tid & 63;
  __shared__ float4 s_box[KPRE];
  __shared__ float s_area[KPRE];
  for (int t = tid; t < KPRE; t += 256) {
    float4 v = g_tbox[(size_t)b * KPAD + t];
    s_box[t] = v;
    s_area[t] = (v.z - v.x) * (v.w - v.y);
  }
  __syncthreads();

  // 64 rows x 16 words = 1024 wave-tasks, strided over 4 waves
  for (int task = wave; task < 64 * 16; task += 4) {
    int r = task >> 4;
    int w = task & 15;
    int i = c * 64 + r;
    if (i >= KPRE) continue;               // wave-uniform
    ull word = 0;
    if (w * 64 + 63 > i) {                 // word intersects upper triangle
      int j = w * 64 + lane;
      bool p = false;
      if (j > i && j < KPRE) {
        float4 bi = s_box[i];              // broadcast
        float4 bj = s_box[j];
        float ltx = fmaxf(bi.x, bj.x);
        float lty = fmaxf(bi.y, bj.y);
        float rbx = fminf(bi.z, bj.z);
        float rby = fminf(bi.w, bj.w);
        float wx = fmaxf(rbx - ltx, 0.f);
        float wy = fmaxf(rby - lty, 0.f);
        float inter = wx * wy;
        float den = ((s_area[i] + s_area[j]) - inter) + 1e-7f;
        p = (inter / den) > IOUTHR;
      }
      word = __ballot(p);
    }
    if (lane == 0) g_sup[((size_t)b * KPAD + i) * 16 + w] = word;
  }
}

// ---------------- Kernel 4: sequential NMS + parallel selection + output ----------------
__global__ __launch_bounds__(64) void k_nms(
    const ull* __restrict__ g_sup,
    const float* __restrict__ g_tscore,
    const float4* __restrict__ g_tbox,
    const int* __restrict__ g_tcls,
    const float* __restrict__ g_tdist,
    float* __restrict__ out)
{
  int b = blockIdx.x;
  int lane = threadIdx.x;
  __shared__ ull rowbuf[64][16];
  __shared__ float s_score[KPAD];
  __shared__ ull s_removedw[16];
  __shared__ ull s_valid[16];
  __shared__ int s_vpre[17];
  __shared__ int s_ipre[17];
  __shared__ int s_sel[MAXDET];
  __shared__ int s_flag[MAXDET];

  for (int t = lane; t < KPAD; t += 64)
    s_score[t] = g_tscore[(size_t)b * KPAD + t];

  ull rem = 0;  // lane w (mod 16) mirrors removed word w
  const ull* sup = g_sup + (size_t)b * KPAD * 16;
  for (int chunk = 0; chunk < 16; ++chunk) {
    int c0 = chunk * 64;
    __syncthreads();
    for (int t = lane; t < 64 * 16; t += 64)
      rowbuf[t >> 4][t & 15] = sup[(size_t)(c0 + (t >> 4)) * 16 + (t & 15)];
    __syncthreads();
    int imax = min(64, KPRE - c0);
    for (int ii = 0; ii < imax; ++ii) {
      ull remw = __shfl(rem, chunk);          // word containing bit for i=c0+ii
      bool kept = !((remw >> ii) & 1ull);
      if (kept) rem |= rowbuf[ii][lane & 15];
    }
  }
  if (lane < 16) s_removedw[lane] = rem;
  __syncthreads();

  // valid mask: kept && score > CONF  (bits for c >= KPRE are 0)
  for (int k = 0; k < 16; ++k) {
    int c = k * 64 + lane;
    bool v = (c < KPRE) && (s_score[c] > CONF) && !((s_removedw[k] >> lane) & 1ull);
    ull m = __ballot(v);
    if (lane == 0) s_valid[k] = m;
  }
  __syncthreads();

  // prefix counts (valid / invalid among c < KPRE)
  if (lane == 0) {
    int v = 0, iv = 0;
    for (int k = 0; k < 16; ++k) {
      s_vpre[k] = v; s_ipre[k] = iv;
      int nval = (k == 15) ? (KPRE - 15 * 64) : 64;
      int pv = __popcll(s_valid[k]);
      v += pv; iv += nval - pv;
    }
    s_vpre[16] = v; s_ipre[16] = iv;
  }
  __syncthreads();

  // parallel scatter: valid entries in array order, then invalid (tied -1.0)
  int totValid = s_vpre[16];
  for (int k = 0; k < 16; ++k) {
    int c = k * 64 + lane;
    if (c >= KPRE) continue;
    ull wv = s_valid[k];
    ull ltmask = (1ull << lane) - 1ull;
    bool v = (wv >> lane) & 1ull;
    int below = __popcll(wv & ltmask);
    if (v) {
      int rank = s_vpre[k] + below;
      if (rank < MAXDET) { s_sel[rank] = c; s_flag[rank] = 1; }
    } else {
      int rank = totValid + s_ipre[k] + (lane - below);
      if (rank < MAXDET) { s_sel[rank] = c; s_flag[rank] = 0; }
    }
  }
  __syncthreads();

  float* obox = out;                                 // [B][100][4]
  float* osc  = out + (size_t)BATCH * MAXDET * 4;    // [B][100]
  float* ocls = out + (size_t)BATCH * MAXDET * 5;    // [B][100]
  float* odst = out + (size_t)BATCH * MAXDET * 6;    // [B][100][1]
  float* oval = out + (size_t)BATCH * MAXDET * 7;    // [B][100]

  for (int s = lane; s < MAXDET; s += 64) {
    int i = s_sel[s];
    int fl = s_flag[s];
    size_t src = (size_t)b * KPAD + i;
    float4 bx = g_tbox[src];
    float scv = fl ? s_score[i] : -1.0f;
    float clv = (float)g_tcls[src];
    float ddv = g_tdist[src];
    size_t o = (size_t)b * MAXDET + s;
    obox[o * 4 + 0] = bx.x;
    obox[o * 4 + 1] = bx.y;
    obox[o * 4 + 2] = bx.z;
    obox[o * 4 + 3] = bx.w;
    osc[o] = scv;
    ocls[o] = clv;
    odst[o] = ddv;
    oval[o] = fl ? 1.0f : 0.0f;
  }
}

extern "C" void kernel_launch(void* const* d_in, const int* in_sizes, int n_in,
                              void* d_out, int out_size, void* d_ws, size_t ws_size,
                              hipStream_t stream) {
  const float* pboxes = (const float*)d_in[0];   // (32,8400,64)
  const float* pcls   = (const float*)d_in[1];   // (32,8400,80)
  const float* pdist  = (const float*)d_in[2];   // (32,8400,1)
  // d_in[3] = images, unused by the reference computation
  float* out = (float*)d_out;

  char* ws = (char*)d_ws;
  size_t nBN = (size_t)BATCH * NANCH;
  size_t off = 0;
  float*  g_scores = (float*)(ws + off);  off += nBN * 4;
  float4* g_boxes  = (float4*)(ws + off); off += nBN * 16;
  int*    g_cls    = (int*)(ws + off);    off += nBN * 4;
  float*  g_tscore = (float*)(ws + off);  off += (size_t)BATCH * KPAD * 4;
  float4* g_tbox   = (float4*)(ws + off); off += (size_t)BATCH * KPAD * 16;
  int*    g_tcls   = (int*)(ws + off);    off += (size_t)BATCH * KPAD * 4;
  float*  g_tdist  = (float*)(ws + off);  off += (size_t)BATCH * KPAD * 4;
  ull*    g_sup    = (ull*)(ws + off);    off += (size_t)BATCH * KPAD * 16 * 8;

  int total = BATCH * NANCH;
  k_decode<<<(total + 255) / 256, 256, 0, stream>>>(pboxes, pcls, g_scores, g_boxes, g_cls);
  k_topk<<<BATCH, 1024, 0, stream>>>(g_scores, g_boxes, g_cls, pdist,
                                     g_tscore, g_tbox, g_tcls, g_tdist);
  dim3 giou(BATCH, 16);
  k_iou<<<giou, 256, 0, stream>>>(g_tbox, g_sup);
  k_nms<<<BATCH, 64, 0, stream>>>(g_sup, g_tscore, g_tbox, g_tcls, g_tdist, out);
}

// Round 3
// 236.842 us; speedup vs baseline: 1.4668x; 1.0013x over previous
//
#include <hip/hip_runtime.h>
#include <stdint.h>

#define BATCH 32
#define NANCH 8400
#define NCLS 80
#define KPRE 1000
#define KPAD 1024
#define MAXDET 100
#define CONF 0.2f
#define IOUTHR 0.7f

typedef unsigned long long ull;

// monotonic map: float -> uint32 preserving total order
__device__ __forceinline__ uint32_t fmap(float f) {
  uint32_t u = __float_as_uint(f);
  return (u & 0x80000000u) ? ~u : (u | 0x80000000u);
}

// ---------------- Kernel 1: decode (DFL + class max/argmax + box) ----------------
__global__ __launch_bounds__(256) void k_decode(
    const float* __restrict__ pboxes,   // [B][N][64]
    const float* __restrict__ pcls,     // [B][N][80]
    float* __restrict__ g_scores,       // [B][N]
    float4* __restrict__ g_boxes,       // [B][N]
    int* __restrict__ g_cls)            // [B][N]
{
  int gid = blockIdx.x * blockDim.x + threadIdx.x;
  if (gid >= BATCH * NANCH) return;
  int n = gid % NANCH;

  // class max / argmax (first occurrence wins: strict >)
  const float4* pc = (const float4*)(pcls + (size_t)gid * NCLS);
  float best = -3.402823466e38f;
  int bidx = 0;
  #pragma unroll
  for (int k = 0; k < NCLS / 4; ++k) {
    float4 v = pc[k];
    if (v.x > best) { best = v.x; bidx = 4 * k + 0; }
    if (v.y > best) { best = v.y; bidx = 4 * k + 1; }
    if (v.z > best) { best = v.z; bidx = 4 * k + 2; }
    if (v.w > best) { best = v.w; bidx = 4 * k + 3; }
  }

  // DFL: softmax over 16 then dot with arange(16), matching JAX order
  const float4* pb = (const float4*)(pboxes + (size_t)gid * 64);
  float dist[4];
  #pragma unroll
  for (int k = 0; k < 4; ++k) {
    float v[16];
    #pragma unroll
    for (int q = 0; q < 4; ++q) {
      float4 t = pb[k * 4 + q];
      v[q * 4 + 0] = t.x; v[q * 4 + 1] = t.y; v[q * 4 + 2] = t.z; v[q * 4 + 3] = t.w;
    }
    float m = v[0];
    #pragma unroll
    for (int r = 1; r < 16; ++r) m = fmaxf(m, v[r]);
    float e[16];
    float s = 0.f;
    #pragma unroll
    for (int r = 0; r < 16; ++r) { e[r] = expf(v[r] - m); s += e[r]; }
    float acc = 0.f;
    #pragma unroll
    for (int r = 0; r < 16; ++r) acc += (e[r] / s) * (float)r;
    dist[k] = acc;
  }

  // anchors: levels 80x80(s8), 40x40(s16), 20x20(s32); anchor=(col+0.5, row+0.5)
  int n0, W; float sf;
  if (n < 6400)      { n0 = n;        W = 80; sf = 8.f;  }
  else if (n < 8000) { n0 = n - 6400; W = 40; sf = 16.f; }
  else               { n0 = n - 8000; W = 20; sf = 32.f; }
  float ax = (float)(n0 % W) + 0.5f;
  float ay = (float)(n0 / W) + 0.5f;

  float4 bx;
  bx.x = (ax - dist[0]) * sf;
  bx.y = (ay - dist[1]) * sf;
  bx.z = (ax + dist[2]) * sf;
  bx.w = (ay + dist[3]) * sf;

  g_boxes[gid] = bx;
  g_scores[gid] = best;
  g_cls[gid] = bidx;
}

// ---------------- Kernel 2: exact stable top-1000 per batch ----------------
// composite 46-bit key: (fmap(score) << 14) | (NANCH-1-i). All keys distinct.
#define KBITS 46
#define NITER 46
#define NQ 9   // ceil(8400/1024)

__global__ __launch_bounds__(1024) void k_topk(
    const float* __restrict__ g_scores,
    const float4* __restrict__ g_boxes,
    const int* __restrict__ g_cls,
    const float* __restrict__ g_dist_in,   // [B][N][1]
    float* __restrict__ g_tscore,          // [B][KPAD]
    float4* __restrict__ g_tbox,           // [B][KPAD]
    int* __restrict__ g_tcls,              // [B][KPAD]
    float* __restrict__ g_tdist)           // [B][KPAD]
{
  int b = blockIdx.x;
  int tid = threadIdx.x;
  int lane = tid & 63;
  __shared__ float ls[NANCH];
  __shared__ ull skeys[KPAD];
  __shared__ int s_cnt[NITER];
  __shared__ int s_pos;

  const float* sc = g_scores + (size_t)b * NANCH;

  // load scores to LDS + build per-thread keys in registers (static indexing)
  ull key[NQ];
  #pragma unroll
  for (int q = 0; q < NQ; ++q) {
    int i = tid + q * 1024;
    if (i < NANCH) {
      float x = sc[i];
      ls[i] = x;
      key[q] = ((ull)fmap(x) << 14) | (ull)(uint32_t)(NANCH - 1 - i);
    } else {
      key[q] = 0ull;  // never selected (mid >= 1 always; real keys > 0)
    }
  }
  if (tid < NITER) s_cnt[tid] = 0;
  if (tid == 0) s_pos = 0;
  __syncthreads();

  // bisection for exact 1000th-largest key: 46 rounds, 1 barrier each
  ull lo = 0, hi = 1ull << KBITS;
  for (int it = 0; it < NITER; ++it) {
    ull mid = lo + ((hi - lo) >> 1);
    int local = 0;
    #pragma unroll
    for (int q = 0; q < NQ; ++q) local += (key[q] >= mid) ? 1 : 0;
    #pragma unroll
    for (int off = 32; off > 0; off >>= 1) local += __shfl_down(local, off);
    if (lane == 0) atomicAdd(&s_cnt[it], local);
    __syncthreads();
    int cnt = s_cnt[it];
    if (cnt >= KPRE) lo = mid; else hi = mid;
  }
  // lo == exact 1000th largest key; exactly KPRE keys >= lo

  // compact selected keys to LDS
  #pragma unroll
  for (int q = 0; q < NQ; ++q) {
    bool sel = (key[q] >= lo);
    ull m = __ballot(sel);
    int base = 0;
    if (lane == 0) base = atomicAdd(&s_pos, __popcll(m));
    base = __shfl(base, 0);
    if (sel) skeys[base + __popcll(m & ((1ull << lane) - 1ull))] = key[q];
  }
  if (tid >= KPRE) skeys[tid] = 0ull;  // pad sorts last
  __syncthreads();

  // bitonic sort 1024 keys, descending
  for (int k = 2; k <= KPAD; k <<= 1) {
    for (int j = k >> 1; j > 0; j >>= 1) {
      int i = tid;
      int ixj = i ^ j;
      if (ixj > i) {
        ull a = skeys[i], c = skeys[ixj];
        bool descDir = ((i & k) == 0);
        bool doSwap = descDir ? (a < c) : (a > c);
        if (doSwap) { skeys[i] = c; skeys[ixj] = a; }
      }
      __syncthreads();
    }
  }

  if (tid < KPRE) {
    ull kk = skeys[tid];
    int n = (NANCH - 1) - (int)(uint32_t)(kk & 0x3FFFull);
    size_t src = (size_t)b * NANCH + n;
    size_t dst = (size_t)b * KPAD + tid;
    g_tscore[dst] = ls[n];
    g_tbox[dst] = g_boxes[src];
    g_tcls[dst] = g_cls[src];
    g_tdist[dst] = g_dist_in[src];
  }
}

// ---------------- Kernel 3: suppression bit-matrix (1 word per wave-task) ----------------
__global__ __launch_bounds__(256) void k_iou(
    const float4* __restrict__ g_tbox,
    ull* __restrict__ g_sup)              // [B][KPAD][16]
{
  int b = blockIdx.x;
  int c = blockIdx.y;            // row-chunk: rows [c*64, c*64+64)
  int tid = threadIdx.x;
  int wave = tid >> 6;           // 4 waves/block
  int lane = tid & 63;
  __shared__ float4 s_box[KPRE];
  __shared__ float s_area[KPRE];
  for (int t = tid; t < KPRE; t += 256) {
    float4 v = g_tbox[(size_t)b * KPAD + t];
    s_box[t] = v;
    s_area[t] = (v.z - v.x) * (v.w - v.y);
  }
  __syncthreads();

  // 64 rows x 16 words = 1024 wave-tasks, strided over 4 waves
  for (int task = wave; task < 64 * 16; task += 4) {
    int r = task >> 4;
    int w = task & 15;
    int i = c * 64 + r;
    if (i >= KPRE) continue;               // wave-uniform
    ull word = 0;
    if (w * 64 + 63 > i) {                 // word intersects upper triangle
      int j = w * 64 + lane;
      bool p = false;
      if (j > i && j < KPRE) {
        float4 bi = s_box[i];              // broadcast
        float4 bj = s_box[j];
        float ltx = fmaxf(bi.x, bj.x);
        float lty = fmaxf(bi.y, bj.y);
        float rbx = fminf(bi.z, bj.z);
        float rby = fminf(bi.w, bj.w);
        float wx = fmaxf(rbx - ltx, 0.f);
        float wy = fmaxf(rby - lty, 0.f);
        float inter = wx * wy;
        float den = ((s_area[i] + s_area[j]) - inter) + 1e-7f;
        p = (inter / den) > IOUTHR;
      }
      word = __ballot(p);
    }
    if (lane == 0) g_sup[((size_t)b * KPAD + i) * 16 + w] = word;
  }
}

// ---------------- Kernel 4: sequential NMS + parallel selection + output ----------------
__global__ __launch_bounds__(64) void k_nms(
    const ull* __restrict__ g_sup,
    const float* __restrict__ g_tscore,
    const float4* __restrict__ g_tbox,
    const int* __restrict__ g_tcls,
    const float* __restrict__ g_tdist,
    float* __restrict__ out)
{
  int b = blockIdx.x;
  int lane = threadIdx.x;
  __shared__ ull rowbuf[64][16];
  __shared__ float s_score[KPAD];
  __shared__ ull s_removedw[16];
  __shared__ ull s_valid[16];
  __shared__ int s_vpre[17];
  __shared__ int s_ipre[17];
  __shared__ int s_sel[MAXDET];
  __shared__ int s_flag[MAXDET];

  for (int t = lane; t < KPAD; t += 64)
    s_score[t] = g_tscore[(size_t)b * KPAD + t];

  ull rem = 0;  // lane w (mod 16) mirrors removed word w
  const ull* sup = g_sup + (size_t)b * KPAD * 16;
  for (int chunk = 0; chunk < 16; ++chunk) {
    int c0 = chunk * 64;
    __syncthreads();
    for (int t = lane; t < 64 * 16; t += 64)
      rowbuf[t >> 4][t & 15] = sup[(size_t)(c0 + (t >> 4)) * 16 + (t & 15)];
    __syncthreads();
    int imax = min(64, KPRE - c0);
    for (int ii = 0; ii < imax; ++ii) {
      ull remw = __shfl(rem, chunk);          // word containing bit for i=c0+ii
      bool kept = !((remw >> ii) & 1ull);
      if (kept) rem |= rowbuf[ii][lane & 15];
    }
  }
  if (lane < 16) s_removedw[lane] = rem;
  __syncthreads();

  // valid mask: kept && score > CONF  (bits for c >= KPRE are 0)
  for (int k = 0; k < 16; ++k) {
    int c = k * 64 + lane;
    bool v = (c < KPRE) && (s_score[c] > CONF) && !((s_removedw[k] >> lane) & 1ull);
    ull m = __ballot(v);
    if (lane == 0) s_valid[k] = m;
  }
  __syncthreads();

  // prefix counts (valid / invalid among c < KPRE)
  if (lane == 0) {
    int v = 0, iv = 0;
    for (int k = 0; k < 16; ++k) {
      s_vpre[k] = v; s_ipre[k] = iv;
      int nval = (k == 15) ? (KPRE - 15 * 64) : 64;
      int pv = __popcll(s_valid[k]);
      v += pv; iv += nval - pv;
    }
    s_vpre[16] = v; s_ipre[16] = iv;
  }
  __syncthreads();

  // parallel scatter: valid entries in array order, then invalid (tied -1.0)
  int totValid = s_vpre[16];
  for (int k = 0; k < 16; ++k) {
    int c = k * 64 + lane;
    if (c >= KPRE) continue;
    ull wv = s_valid[k];
    ull ltmask = (1ull << lane) - 1ull;
    bool v = (wv >> lane) & 1ull;
    int below = __popcll(wv & ltmask);
    if (v) {
      int rank = s_vpre[k] + below;
      if (rank < MAXDET) { s_sel[rank] = c; s_flag[rank] = 1; }
    } else {
      int rank = totValid + s_ipre[k] + (lane - below);
      if (rank < MAXDET) { s_sel[rank] = c; s_flag[rank] = 0; }
    }
  }
  __syncthreads();

  float* obox = out;                                 // [B][100][4]
  float* osc  = out + (size_t)BATCH * MAXDET * 4;    // [B][100]
  float* ocls = out + (size_t)BATCH * MAXDET * 5;    // [B][100]
  float* odst = out + (size_t)BATCH * MAXDET * 6;    // [B][100][1]
  float* oval = out + (size_t)BATCH * MAXDET * 7;    // [B][100]

  for (int s = lane; s < MAXDET; s += 64) {
    int i = s_sel[s];
    int fl = s_flag[s];
    size_t src = (size_t)b * KPAD + i;
    float4 bx = g_tbox[src];
    float scv = fl ? s_score[i] : -1.0f;
    float clv = (float)g_tcls[src];
    float ddv = g_tdist[src];
    size_t o = (size_t)b * MAXDET + s;
    obox[o * 4 + 0] = bx.x;
    obox[o * 4 + 1] = bx.y;
    obox[o * 4 + 2] = bx.z;
    obox[o * 4 + 3] = bx.w;
    osc[o] = scv;
    ocls[o] = clv;
    odst[o] = ddv;
    oval[o] = fl ? 1.0f : 0.0f;
  }
}

extern "C" void kernel_launch(void* const* d_in, const int* in_sizes, int n_in,
                              void* d_out, int out_size, void* d_ws, size_t ws_size,
                              hipStream_t stream) {
  const float* pboxes = (const float*)d_in[0];   // (32,8400,64)
  const float* pcls   = (const float*)d_in[1];   // (32,8400,80)
  const float* pdist  = (const float*)d_in[2];   // (32,8400,1)
  // d_in[3] = images, unused by the reference computation
  float* out = (float*)d_out;

  char* ws = (char*)d_ws;
  size_t nBN = (size_t)BATCH * NANCH;
  size_t off = 0;
  float*  g_scores = (float*)(ws + off);  off += nBN * 4;
  float4* g_boxes  = (float4*)(ws + off); off += nBN * 16;
  int*    g_cls    = (int*)(ws + off);    off += nBN * 4;
  float*  g_tscore = (float*)(ws + off);  off += (size_t)BATCH * KPAD * 4;
  float4* g_tbox   = (float4*)(ws + off); off += (size_t)BATCH * KPAD * 16;
  int*    g_tcls   = (int*)(ws + off);    off += (size_t)BATCH * KPAD * 4;
  float*  g_tdist  = (float*)(ws + off);  off += (size_t)BATCH * KPAD * 4;
  ull*    g_sup    = (ull*)(ws + off);    off += (size_t)BATCH * KPAD * 16 * 8;

  int total = BATCH * NANCH;
  k_decode<<<(total + 255) / 256, 256, 0, stream>>>(pboxes, pcls, g_scores, g_boxes, g_cls);
  k_topk<<<BATCH, 1024, 0, stream>>>(g_scores, g_boxes, g_cls, pdist,
                                     g_tscore, g_tbox, g_tcls, g_tdist);
  dim3 giou(BATCH, 16);
  k_iou<<<giou, 256, 0, stream>>>(g_tbox, g_sup);
  k_nms<<<BATCH, 64, 0, stream>>>(g_sup, g_tscore, g_tbox, g_tcls, g_tdist, out);
}

// Round 4
// 199.046 us; speedup vs baseline: 1.7453x; 1.1899x over previous
//
#include <hip/hip_runtime.h>
#include <stdint.h>

#define BATCH 32
#define NANCH 8400
#define NCLS 80
#define KPRE 1000
#define KPAD 1024
#define MAXDET 100
#define CONF 0.2f
#define IOUTHR 0.7f

typedef unsigned long long ull;

// monotonic map: float -> uint32 preserving total order
__device__ __forceinline__ uint32_t fmap(float f) {
  uint32_t u = __float_as_uint(f);
  return (u & 0x80000000u) ? ~u : (u | 0x80000000u);
}

__device__ __forceinline__ ull readlane64(ull v, int lane) {
  uint32_t lo = __builtin_amdgcn_readlane((uint32_t)(v & 0xffffffffull), lane);
  uint32_t hi = __builtin_amdgcn_readlane((uint32_t)(v >> 32), lane);
  return ((ull)hi << 32) | (ull)lo;
}

// ---------------- Kernel 1: decode (DFL + class max/argmax + box) ----------------
__global__ __launch_bounds__(256) void k_decode(
    const float* __restrict__ pboxes,   // [B][N][64]
    const float* __restrict__ pcls,     // [B][N][80]
    float* __restrict__ g_scores,       // [B][N]
    float4* __restrict__ g_boxes,       // [B][N]
    int* __restrict__ g_cls)            // [B][N]
{
  int gid = blockIdx.x * blockDim.x + threadIdx.x;
  if (gid >= BATCH * NANCH) return;
  int n = gid % NANCH;

  // class max / argmax (first occurrence wins: strict >)
  const float4* pc = (const float4*)(pcls + (size_t)gid * NCLS);
  float best = -3.402823466e38f;
  int bidx = 0;
  #pragma unroll
  for (int k = 0; k < NCLS / 4; ++k) {
    float4 v = pc[k];
    if (v.x > best) { best = v.x; bidx = 4 * k + 0; }
    if (v.y > best) { best = v.y; bidx = 4 * k + 1; }
    if (v.z > best) { best = v.z; bidx = 4 * k + 2; }
    if (v.w > best) { best = v.w; bidx = 4 * k + 3; }
  }

  // DFL: softmax over 16 then dot with arange(16), matching JAX order
  const float4* pb = (const float4*)(pboxes + (size_t)gid * 64);
  float dist[4];
  #pragma unroll
  for (int k = 0; k < 4; ++k) {
    float v[16];
    #pragma unroll
    for (int q = 0; q < 4; ++q) {
      float4 t = pb[k * 4 + q];
      v[q * 4 + 0] = t.x; v[q * 4 + 1] = t.y; v[q * 4 + 2] = t.z; v[q * 4 + 3] = t.w;
    }
    float m = v[0];
    #pragma unroll
    for (int r = 1; r < 16; ++r) m = fmaxf(m, v[r]);
    float e[16];
    float s = 0.f;
    #pragma unroll
    for (int r = 0; r < 16; ++r) { e[r] = expf(v[r] - m); s += e[r]; }
    float acc = 0.f;
    #pragma unroll
    for (int r = 0; r < 16; ++r) acc += (e[r] / s) * (float)r;
    dist[k] = acc;
  }

  // anchors: levels 80x80(s8), 40x40(s16), 20x20(s32); anchor=(col+0.5, row+0.5)
  int n0, W; float sf;
  if (n < 6400)      { n0 = n;        W = 80; sf = 8.f;  }
  else if (n < 8000) { n0 = n - 6400; W = 40; sf = 16.f; }
  else               { n0 = n - 8000; W = 20; sf = 32.f; }
  float ax = (float)(n0 % W) + 0.5f;
  float ay = (float)(n0 / W) + 0.5f;

  float4 bx;
  bx.x = (ax - dist[0]) * sf;
  bx.y = (ay - dist[1]) * sf;
  bx.z = (ax + dist[2]) * sf;
  bx.w = (ay + dist[3]) * sf;

  g_boxes[gid] = bx;
  g_scores[gid] = best;
  g_cls[gid] = bidx;
}

// ---------------- Kernel 2: exact stable top-1000 per batch ----------------
// composite 46-bit key: (fmap(score) << 14) | (NANCH-1-i). All keys distinct.
#define KBITS 46
#define NITER 46
#define NQ 9   // ceil(8400/1024)

__global__ __launch_bounds__(1024) void k_topk(
    const float* __restrict__ g_scores,
    const float4* __restrict__ g_boxes,
    const int* __restrict__ g_cls,
    const float* __restrict__ g_dist_in,   // [B][N][1]
    float* __restrict__ g_tscore,          // [B][KPAD]
    float4* __restrict__ g_tbox,           // [B][KPAD]
    int* __restrict__ g_tcls,              // [B][KPAD]
    float* __restrict__ g_tdist)           // [B][KPAD]
{
  int b = blockIdx.x;
  int tid = threadIdx.x;
  int lane = tid & 63;
  __shared__ float ls[NANCH];
  __shared__ ull skeys[KPAD];
  __shared__ int s_cnt[NITER];
  __shared__ int s_pos;

  const float* sc = g_scores + (size_t)b * NANCH;

  // load scores to LDS + build per-thread keys in registers (static indexing)
  ull key[NQ];
  #pragma unroll
  for (int q = 0; q < NQ; ++q) {
    int i = tid + q * 1024;
    if (i < NANCH) {
      float x = sc[i];
      ls[i] = x;
      key[q] = ((ull)fmap(x) << 14) | (ull)(uint32_t)(NANCH - 1 - i);
    } else {
      key[q] = 0ull;  // never selected (mid >= 1 always; real keys > 0)
    }
  }
  if (tid < NITER) s_cnt[tid] = 0;
  if (tid == 0) s_pos = 0;
  __syncthreads();

  // bisection for exact 1000th-largest key: 46 rounds, 1 barrier each
  ull lo = 0, hi = 1ull << KBITS;
  for (int it = 0; it < NITER; ++it) {
    ull mid = lo + ((hi - lo) >> 1);
    int local = 0;
    #pragma unroll
    for (int q = 0; q < NQ; ++q) local += (key[q] >= mid) ? 1 : 0;
    #pragma unroll
    for (int off = 32; off > 0; off >>= 1) local += __shfl_down(local, off);
    if (lane == 0) atomicAdd(&s_cnt[it], local);
    __syncthreads();
    int cnt = s_cnt[it];
    if (cnt >= KPRE) lo = mid; else hi = mid;
  }
  // lo == exact 1000th largest key; exactly KPRE keys >= lo

  // compact selected keys to LDS
  #pragma unroll
  for (int q = 0; q < NQ; ++q) {
    bool sel = (key[q] >= lo);
    ull m = __ballot(sel);
    int base = 0;
    if (lane == 0) base = atomicAdd(&s_pos, __popcll(m));
    base = __shfl(base, 0);
    if (sel) skeys[base + __popcll(m & ((1ull << lane) - 1ull))] = key[q];
  }
  if (tid >= KPRE) skeys[tid] = 0ull;  // pad sorts last
  __syncthreads();

  // bitonic sort 1024 keys, descending
  for (int k = 2; k <= KPAD; k <<= 1) {
    for (int j = k >> 1; j > 0; j >>= 1) {
      int i = tid;
      int ixj = i ^ j;
      if (ixj > i) {
        ull a = skeys[i], c = skeys[ixj];
        bool descDir = ((i & k) == 0);
        bool doSwap = descDir ? (a < c) : (a > c);
        if (doSwap) { skeys[i] = c; skeys[ixj] = a; }
      }
      __syncthreads();
    }
  }

  if (tid < KPRE) {
    ull kk = skeys[tid];
    int n = (NANCH - 1) - (int)(uint32_t)(kk & 0x3FFFull);
    size_t src = (size_t)b * NANCH + n;
    size_t dst = (size_t)b * KPAD + tid;
    g_tscore[dst] = ls[n];
    g_tbox[dst] = g_boxes[src];
    g_tcls[dst] = g_cls[src];
    g_tdist[dst] = g_dist_in[src];
  }
}

// ---------------- Kernel 3: suppression bit-matrix (1 word per wave-task) ----------------
__global__ __launch_bounds__(256) void k_iou(
    const float4* __restrict__ g_tbox,
    ull* __restrict__ g_sup,              // [B][KPAD][16] row-major
    ull* __restrict__ g_diag)             // [B][16][64] diag blocks
{
  int b = blockIdx.x;
  int c = blockIdx.y;            // row-chunk: rows [c*64, c*64+64)
  int tid = threadIdx.x;
  int wave = tid >> 6;           // 4 waves/block
  int lane = tid & 63;
  __shared__ float4 s_box[KPRE];
  __shared__ float s_area[KPRE];
  for (int t = tid; t < KPRE; t += 256) {
    float4 v = g_tbox[(size_t)b * KPAD + t];
    s_box[t] = v;
    s_area[t] = (v.z - v.x) * (v.w - v.y);
  }
  __syncthreads();

  // 64 rows x 16 words = 1024 wave-tasks, strided over 4 waves
  for (int task = wave; task < 64 * 16; task += 4) {
    int r = task >> 4;
    int w = task & 15;
    int i = c * 64 + r;
    if (i >= KPRE) continue;               // wave-uniform
    ull word = 0;
    if (w * 64 + 63 > i) {                 // word intersects upper triangle
      int j = w * 64 + lane;
      bool p = false;
      if (j > i && j < KPRE) {
        float4 bi = s_box[i];              // broadcast
        float4 bj = s_box[j];
        float ltx = fmaxf(bi.x, bj.x);
        float lty = fmaxf(bi.y, bj.y);
        float rbx = fminf(bi.z, bj.z);
        float rby = fminf(bi.w, bj.w);
        float wx = fmaxf(rbx - ltx, 0.f);
        float wy = fmaxf(rby - lty, 0.f);
        float inter = wx * wy;
        float den = ((s_area[i] + s_area[j]) - inter) + 1e-7f;
        p = (inter / den) > IOUTHR;
      }
      word = __ballot(p);
    }
    if (lane == 0) {
      g_sup[((size_t)b * KPAD + i) * 16 + w] = word;
      if (w == c) g_diag[((size_t)b * 16 + c) * 64 + r] = word;
    }
  }
}

// ---------------- Kernel 4: scalar-chain NMS + parallel selection + output ----------------
__global__ __launch_bounds__(64) void k_nms(
    const ull* __restrict__ g_sup,
    const ull* __restrict__ g_diag,
    const float* __restrict__ g_tscore,
    const float4* __restrict__ g_tbox,
    const int* __restrict__ g_tcls,
    const float* __restrict__ g_tdist,
    float* __restrict__ out)
{
  int b = blockIdx.x;
  int lane = threadIdx.x;
  __shared__ __align__(16) ull rowbuf[2][64 * 16];   // 16 KB double buffer
  __shared__ float s_score[KPAD];
  __shared__ ull s_keptw[16];
  __shared__ int s_vpre[17];
  __shared__ int s_ipre[17];
  __shared__ int s_sel[MAXDET];
  __shared__ int s_flag[MAXDET];

  for (int t = lane; t < KPAD; t += 64)
    s_score[t] = g_tscore[(size_t)b * KPAD + t];

  const char* supb = (const char*)(g_sup + (size_t)b * KPAD * 16);
  const ull* diagb = g_diag + (size_t)b * 16 * 64;

  // prefetch chunk 0 (8 KB) into rowbuf[0] via global_load_lds width-16
  #pragma unroll
  for (int k = 0; k < 8; ++k) {
    const void* gp = supb + (size_t)k * 1024 + (size_t)lane * 16;
    void* lp = (char*)&rowbuf[0][0] + k * 1024;
    __builtin_amdgcn_global_load_lds(
        (const __attribute__((address_space(1))) uint32_t*)gp,
        (__attribute__((address_space(3))) uint32_t*)lp, 16, 0, 0);
  }
  ull diag = diagb[0 * 64 + lane];   // diag words for chunk 0

  // rem4: lane (q=lane>>4, w=lane&15) accumulates word w over kept rows ii with (ii&3)==q
  ull rem4 = 0;
  int w = lane & 15;
  int q = lane >> 4;
  int cur = 0;

  for (int c = 0; c < 16; ++c) {
    asm volatile("s_waitcnt vmcnt(0)" ::: "memory");  // chunk c staged, diag ready

    ull diag_next = 0;
    if (c < 15) {
      #pragma unroll
      for (int k = 0; k < 8; ++k) {
        const void* gp = supb + (size_t)(c + 1) * 8192 + (size_t)k * 1024 + (size_t)lane * 16;
        void* lp = (char*)&rowbuf[cur ^ 1][0] + k * 1024;
        __builtin_amdgcn_global_load_lds(
            (const __attribute__((address_space(1))) uint32_t*)gp,
            (__attribute__((address_space(3))) uint32_t*)lp, 16, 0, 0);
      }
      diag_next = diagb[(c + 1) * 64 + lane];
    }

    // removed word for this chunk from cross-chunk accumulation
    ull remw = readlane64(rem4, c) | readlane64(rem4, c + 16) |
               readlane64(rem4, c + 32) | readlane64(rem4, c + 48);
    ull chunkmask = (c == 15) ? ((1ull << (KPRE - 15 * 64)) - 1ull) : ~0ull;
    ull alive = ~remw & chunkmask;

    // serial greedy chain — wave-uniform scalar ops + readlane, nothing else
    ull kept = 0;
    while (alive) {
      int ii = __builtin_ctzll(alive);
      kept |= 1ull << ii;
      ull wcur = readlane64(diag, ii);
      alive &= ~(wcur | (1ull << ii));
    }
    if (lane == 0) s_keptw[c] = kept;

    // deferred parallel accumulation: OR all 16 words of kept rows into rem4.
    // lane (q,w) handles rows ii = q + 4*t (static unroll → independent ds_reads)
    #pragma unroll
    for (int t = 0; t < 16; ++t) {
      int ii = q + t * 4;
      ull v = rowbuf[cur][ii * 16 + w];    // always load (pipelined); predicated use
      if ((kept >> ii) & 1ull) rem4 |= v;
    }

    cur ^= 1;
    diag = diag_next;
  }
  __syncthreads();

  // valid mask: kept && score > CONF
  __shared__ ull s_valid[16];
  for (int k = 0; k < 16; ++k) {
    int c = k * 64 + lane;
    bool sv = (c < KPRE) && (s_score[c] > CONF);
    ull m = __ballot(sv) & s_keptw[k];
    if (lane == 0) s_valid[k] = m;
  }
  __syncthreads();

  // prefix counts (valid / invalid among c < KPRE)
  if (lane == 0) {
    int v = 0, iv = 0;
    for (int k = 0; k < 16; ++k) {
      s_vpre[k] = v; s_ipre[k] = iv;
      int nval = (k == 15) ? (KPRE - 15 * 64) : 64;
      int pv = __popcll(s_valid[k]);
      v += pv; iv += nval - pv;
    }
    s_vpre[16] = v; s_ipre[16] = iv;
  }
  __syncthreads();

  // parallel scatter: valid entries in array order, then invalid (tied -1.0)
  int totValid = s_vpre[16];
  for (int k = 0; k < 16; ++k) {
    int c = k * 64 + lane;
    if (c >= KPRE) continue;
    ull wv = s_valid[k];
    ull ltmask = (1ull << lane) - 1ull;
    bool v = (wv >> lane) & 1ull;
    int below = __popcll(wv & ltmask);
    if (v) {
      int rank = s_vpre[k] + below;
      if (rank < MAXDET) { s_sel[rank] = c; s_flag[rank] = 1; }
    } else {
      int rank = totValid + s_ipre[k] + (lane - below);
      if (rank < MAXDET) { s_sel[rank] = c; s_flag[rank] = 0; }
    }
  }
  __syncthreads();

  float* obox = out;                                 // [B][100][4]
  float* osc  = out + (size_t)BATCH * MAXDET * 4;    // [B][100]
  float* ocls = out + (size_t)BATCH * MAXDET * 5;    // [B][100]
  float* odst = out + (size_t)BATCH * MAXDET * 6;    // [B][100][1]
  float* oval = out + (size_t)BATCH * MAXDET * 7;    // [B][100]

  for (int s = lane; s < MAXDET; s += 64) {
    int i = s_sel[s];
    int fl = s_flag[s];
    size_t src = (size_t)b * KPAD + i;
    float4 bx = g_tbox[src];
    float scv = fl ? s_score[i] : -1.0f;
    float clv = (float)g_tcls[src];
    float ddv = g_tdist[src];
    size_t o = (size_t)b * MAXDET + s;
    obox[o * 4 + 0] = bx.x;
    obox[o * 4 + 1] = bx.y;
    obox[o * 4 + 2] = bx.z;
    obox[o * 4 + 3] = bx.w;
    osc[o] = scv;
    ocls[o] = clv;
    odst[o] = ddv;
    oval[o] = fl ? 1.0f : 0.0f;
  }
}

extern "C" void kernel_launch(void* const* d_in, const int* in_sizes, int n_in,
                              void* d_out, int out_size, void* d_ws, size_t ws_size,
                              hipStream_t stream) {
  const float* pboxes = (const float*)d_in[0];   // (32,8400,64)
  const float* pcls   = (const float*)d_in[1];   // (32,8400,80)
  const float* pdist  = (const float*)d_in[2];   // (32,8400,1)
  // d_in[3] = images, unused by the reference computation
  float* out = (float*)d_out;

  char* ws = (char*)d_ws;
  size_t nBN = (size_t)BATCH * NANCH;
  size_t off = 0;
  float*  g_scores = (float*)(ws + off);  off += nBN * 4;
  float4* g_boxes  = (float4*)(ws + off); off += nBN * 16;
  int*    g_cls    = (int*)(ws + off);    off += nBN * 4;
  float*  g_tscore = (float*)(ws + off);  off += (size_t)BATCH * KPAD * 4;
  float4* g_tbox   = (float4*)(ws + off); off += (size_t)BATCH * KPAD * 16;
  int*    g_tcls   = (int*)(ws + off);    off += (size_t)BATCH * KPAD * 4;
  float*  g_tdist  = (float*)(ws + off);  off += (size_t)BATCH * KPAD * 4;
  ull*    g_sup    = (ull*)(ws + off);    off += (size_t)BATCH * KPAD * 16 * 8;
  ull*    g_diag   = (ull*)(ws + off);    off += (size_t)BATCH * 16 * 64 * 8;

  int total = BATCH * NANCH;
  k_decode<<<(total + 255) / 256, 256, 0, stream>>>(pboxes, pcls, g_scores, g_boxes, g_cls);
  k_topk<<<BATCH, 1024, 0, stream>>>(g_scores, g_boxes, g_cls, pdist,
                                     g_tscore, g_tbox, g_tcls, g_tdist);
  dim3 giou(BATCH, 16);
  k_iou<<<giou, 256, 0, stream>>>(g_tbox, g_sup, g_diag);
  k_nms<<<BATCH, 64, 0, stream>>>(g_sup, g_diag, g_tscore, g_tbox, g_tcls, g_tdist, out);
}

// Round 5
// 198.962 us; speedup vs baseline: 1.7460x; 1.0004x over previous
//
#include <hip/hip_runtime.h>
#include <stdint.h>

#define BATCH 32
#define NANCH 8400
#define NCLS 80
#define KPRE 1000
#define KPAD 1024
#define MAXDET 100
#define CONF 0.2f
#define IOUTHR 0.7f

typedef unsigned long long ull;

// monotonic map: float -> uint32 preserving total order
__device__ __forceinline__ uint32_t fmap(float f) {
  uint32_t u = __float_as_uint(f);
  return (u & 0x80000000u) ? ~u : (u | 0x80000000u);
}

__device__ __forceinline__ ull readlane64(ull v, int lane) {
  uint32_t lo = __builtin_amdgcn_readlane((uint32_t)(v & 0xffffffffull), lane);
  uint32_t hi = __builtin_amdgcn_readlane((uint32_t)(v >> 32), lane);
  return ((ull)hi << 32) | (ull)lo;
}

// ---------------- Kernel 1: class score max/argmax only ----------------
__global__ __launch_bounds__(256) void k_score(
    const float* __restrict__ pcls,     // [B][N][80]
    float* __restrict__ g_scores,       // [B][N]
    int* __restrict__ g_cls)            // [B][N]
{
  int gid = blockIdx.x * blockDim.x + threadIdx.x;
  if (gid >= BATCH * NANCH) return;

  // class max / argmax (first occurrence wins: strict >)
  const float4* pc = (const float4*)(pcls + (size_t)gid * NCLS);
  float best = -3.402823466e38f;
  int bidx = 0;
  #pragma unroll
  for (int k = 0; k < NCLS / 4; ++k) {
    float4 v = pc[k];
    if (v.x > best) { best = v.x; bidx = 4 * k + 0; }
    if (v.y > best) { best = v.y; bidx = 4 * k + 1; }
    if (v.z > best) { best = v.z; bidx = 4 * k + 2; }
    if (v.w > best) { best = v.w; bidx = 4 * k + 3; }
  }
  g_scores[gid] = best;
  g_cls[gid] = bidx;
}

// ---------------- Kernel 2: exact stable top-1000 per batch ----------------
// composite 46-bit key: (fmap(score) << 14) | (NANCH-1-i). All keys distinct.
#define NITER2 23   // 2 bits per round: 4^23 = 2^46
#define NQ 9        // ceil(8400/1024)

__global__ __launch_bounds__(1024) void k_topk(
    const float* __restrict__ g_scores,
    const int* __restrict__ g_cls,
    const float* __restrict__ g_dist_in,   // [B][N][1]
    float* __restrict__ g_tscore,          // [B][KPAD]
    int* __restrict__ g_tn,                // [B][KPAD] selected anchor index
    int* __restrict__ g_tcls,              // [B][KPAD]
    float* __restrict__ g_tdist)           // [B][KPAD]
{
  int b = blockIdx.x;
  int tid = threadIdx.x;
  int lane = tid & 63;
  __shared__ float ls[NANCH];
  __shared__ ull skeys[KPAD];
  __shared__ int s_cnt[NITER2][3];
  __shared__ int s_pos;

  const float* sc = g_scores + (size_t)b * NANCH;

  // load scores to LDS + build per-thread keys in registers (static indexing)
  ull key[NQ];
  #pragma unroll
  for (int q = 0; q < NQ; ++q) {
    int i = tid + q * 1024;
    if (i < NANCH) {
      float x = sc[i];
      ls[i] = x;
      key[q] = ((ull)fmap(x) << 14) | (ull)(uint32_t)(NANCH - 1 - i);
    } else {
      key[q] = 0ull;  // never selected (thresholds are always > 0; real keys >= 2^45)
    }
  }
  if (tid < NITER2 * 3) ((int*)s_cnt)[tid] = 0;
  if (tid == 0) s_pos = 0;
  __syncthreads();

  // 4-way bisection for exact 1000th-largest key: 23 rounds, 1 barrier each.
  // invariant: cnt(lo) >= KPRE, cnt(lo+width) < KPRE
  ull lo = 0, width = 1ull << 46;
  for (int it = 0; it < NITER2; ++it) {
    ull d = width >> 2;
    ull t1 = lo + d, t2 = lo + 2 * d, t3 = lo + 3 * d;
    int c1 = 0, c2 = 0, c3 = 0;
    #pragma unroll
    for (int q = 0; q < NQ; ++q) {
      ull k = key[q];
      c1 += (k >= t1) ? 1 : 0;
      c2 += (k >= t2) ? 1 : 0;
      c3 += (k >= t3) ? 1 : 0;
    }
    #pragma unroll
    for (int off = 32; off > 0; off >>= 1) {
      c1 += __shfl_down(c1, off);
      c2 += __shfl_down(c2, off);
      c3 += __shfl_down(c3, off);
    }
    if (lane == 0) {
      atomicAdd(&s_cnt[it][0], c1);
      atomicAdd(&s_cnt[it][1], c2);
      atomicAdd(&s_cnt[it][2], c3);
    }
    __syncthreads();
    int C1 = s_cnt[it][0], C2 = s_cnt[it][1], C3 = s_cnt[it][2];
    if (C3 >= KPRE)      lo = t3;
    else if (C2 >= KPRE) lo = t2;
    else if (C1 >= KPRE) lo = t1;
    width = d;
  }
  // lo == exact 1000th largest key; exactly KPRE keys >= lo

  // compact selected keys to LDS
  #pragma unroll
  for (int q = 0; q < NQ; ++q) {
    bool sel = (key[q] >= lo);
    ull m = __ballot(sel);
    int base = 0;
    if (lane == 0) base = atomicAdd(&s_pos, __popcll(m));
    base = __shfl(base, 0);
    if (sel) skeys[base + __popcll(m & ((1ull << lane) - 1ull))] = key[q];
  }
  if (tid >= KPRE) skeys[tid] = 0ull;  // pad sorts last
  __syncthreads();

  // bitonic sort 1024 keys, descending
  for (int k = 2; k <= KPAD; k <<= 1) {
    for (int j = k >> 1; j > 0; j >>= 1) {
      int i = tid;
      int ixj = i ^ j;
      if (ixj > i) {
        ull a = skeys[i], c = skeys[ixj];
        bool descDir = ((i & k) == 0);
        bool doSwap = descDir ? (a < c) : (a > c);
        if (doSwap) { skeys[i] = c; skeys[ixj] = a; }
      }
      __syncthreads();
    }
  }

  if (tid < KPRE) {
    ull kk = skeys[tid];
    int n = (NANCH - 1) - (int)(uint32_t)(kk & 0x3FFFull);
    size_t src = (size_t)b * NANCH + n;
    size_t dst = (size_t)b * KPAD + tid;
    g_tscore[dst] = ls[n];
    g_tn[dst] = n;
    g_tcls[dst] = g_cls[src];
    g_tdist[dst] = g_dist_in[src];
  }
}

// ---------------- Kernel 2b: DFL box decode for selected anchors only ----------------
__global__ __launch_bounds__(256) void k_boxdec(
    const float* __restrict__ pboxes,   // [B][N][64]
    const int* __restrict__ g_tn,       // [B][KPAD]
    float4* __restrict__ g_tbox)        // [B][KPAD]
{
  int gid = blockIdx.x * blockDim.x + threadIdx.x;
  if (gid >= BATCH * KPRE) return;
  int b = gid / KPRE;
  int s = gid % KPRE;
  int n = g_tn[(size_t)b * KPAD + s];

  // DFL: softmax over 16 then dot with arange(16), matching JAX order
  const float4* pb = (const float4*)(pboxes + ((size_t)b * NANCH + n) * 64);
  float dist[4];
  #pragma unroll
  for (int k = 0; k < 4; ++k) {
    float v[16];
    #pragma unroll
    for (int q = 0; q < 4; ++q) {
      float4 t = pb[k * 4 + q];
      v[q * 4 + 0] = t.x; v[q * 4 + 1] = t.y; v[q * 4 + 2] = t.z; v[q * 4 + 3] = t.w;
    }
    float m = v[0];
    #pragma unroll
    for (int r = 1; r < 16; ++r) m = fmaxf(m, v[r]);
    float e[16];
    float su = 0.f;
    #pragma unroll
    for (int r = 0; r < 16; ++r) { e[r] = expf(v[r] - m); su += e[r]; }
    float acc = 0.f;
    #pragma unroll
    for (int r = 0; r < 16; ++r) acc += (e[r] / su) * (float)r;
    dist[k] = acc;
  }

  // anchors: levels 80x80(s8), 40x40(s16), 20x20(s32); anchor=(col+0.5, row+0.5)
  int n0, W; float sf;
  if (n < 6400)      { n0 = n;        W = 80; sf = 8.f;  }
  else if (n < 8000) { n0 = n - 6400; W = 40; sf = 16.f; }
  else               { n0 = n - 8000; W = 20; sf = 32.f; }
  float ax = (float)(n0 % W) + 0.5f;
  float ay = (float)(n0 / W) + 0.5f;

  float4 bx;
  bx.x = (ax - dist[0]) * sf;
  bx.y = (ay - dist[1]) * sf;
  bx.z = (ax + dist[2]) * sf;
  bx.w = (ay + dist[3]) * sf;

  g_tbox[(size_t)b * KPAD + s] = bx;
}

// ---------------- Kernel 3: suppression bit-matrix (1 word per wave-task) ----------------
__global__ __launch_bounds__(256) void k_iou(
    const float4* __restrict__ g_tbox,
    ull* __restrict__ g_sup,              // [B][KPAD][16] row-major
    ull* __restrict__ g_diag)             // [B][16][64] diag blocks
{
  int b = blockIdx.x;
  int c = blockIdx.y;            // row-chunk: rows [c*64, c*64+64)
  int tid = threadIdx.x;
  int wave = tid >> 6;           // 4 waves/block
  int lane = tid & 63;
  __shared__ float4 s_box[KPRE];
  __shared__ float s_area[KPRE];
  for (int t = tid; t < KPRE; t += 256) {
    float4 v = g_tbox[(size_t)b * KPAD + t];
    s_box[t] = v;
    s_area[t] = (v.z - v.x) * (v.w - v.y);
  }
  __syncthreads();

  // 64 rows x 16 words = 1024 wave-tasks, strided over 4 waves
  for (int task = wave; task < 64 * 16; task += 4) {
    int r = task >> 4;
    int w = task & 15;
    int i = c * 64 + r;
    if (i >= KPRE) continue;               // wave-uniform
    ull word = 0;
    if (w * 64 + 63 > i) {                 // word intersects upper triangle
      int j = w * 64 + lane;
      bool p = false;
      if (j > i && j < KPRE) {
        float4 bi = s_box[i];              // broadcast
        float4 bj = s_box[j];
        float ltx = fmaxf(bi.x, bj.x);
        float lty = fmaxf(bi.y, bj.y);
        float rbx = fminf(bi.z, bj.z);
        float rby = fminf(bi.w, bj.w);
        float wx = fmaxf(rbx - ltx, 0.f);
        float wy = fmaxf(rby - lty, 0.f);
        float inter = wx * wy;
        float den = ((s_area[i] + s_area[j]) - inter) + 1e-7f;
        p = (inter / den) > IOUTHR;
      }
      word = __ballot(p);
    }
    if (lane == 0) {
      g_sup[((size_t)b * KPAD + i) * 16 + w] = word;
      if (w == c) g_diag[((size_t)b * 16 + c) * 64 + r] = word;
    }
  }
}

// ---------------- Kernel 4: scalar-chain NMS + parallel selection + output ----------------
__global__ __launch_bounds__(64) void k_nms(
    const ull* __restrict__ g_sup,
    const ull* __restrict__ g_diag,
    const float* __restrict__ g_tscore,
    const float4* __restrict__ g_tbox,
    const int* __restrict__ g_tcls,
    const float* __restrict__ g_tdist,
    float* __restrict__ out)
{
  int b = blockIdx.x;
  int lane = threadIdx.x;
  __shared__ __align__(16) ull rowbuf[2][64 * 16];   // 16 KB double buffer
  __shared__ float s_score[KPAD];
  __shared__ ull s_keptw[16];
  __shared__ int s_vpre[17];
  __shared__ int s_ipre[17];
  __shared__ int s_sel[MAXDET];
  __shared__ int s_flag[MAXDET];

  for (int t = lane; t < KPAD; t += 64)
    s_score[t] = g_tscore[(size_t)b * KPAD + t];

  const char* supb = (const char*)(g_sup + (size_t)b * KPAD * 16);
  const ull* diagb = g_diag + (size_t)b * 16 * 64;

  // prefetch chunk 0 (8 KB) into rowbuf[0] via global_load_lds width-16
  #pragma unroll
  for (int k = 0; k < 8; ++k) {
    const void* gp = supb + (size_t)k * 1024 + (size_t)lane * 16;
    void* lp = (char*)&rowbuf[0][0] + k * 1024;
    __builtin_amdgcn_global_load_lds(
        (const __attribute__((address_space(1))) uint32_t*)gp,
        (__attribute__((address_space(3))) uint32_t*)lp, 16, 0, 0);
  }
  ull diag = diagb[0 * 64 + lane];   // diag words for chunk 0

  // rem4: lane (q=lane>>4, w=lane&15) accumulates word w over kept rows ii with (ii&3)==q
  ull rem4 = 0;
  int w = lane & 15;
  int q = lane >> 4;
  int cur = 0;

  for (int c = 0; c < 16; ++c) {
    asm volatile("s_waitcnt vmcnt(0)" ::: "memory");  // chunk c staged, diag ready

    ull diag_next = 0;
    if (c < 15) {
      #pragma unroll
      for (int k = 0; k < 8; ++k) {
        const void* gp = supb + (size_t)(c + 1) * 8192 + (size_t)k * 1024 + (size_t)lane * 16;
        void* lp = (char*)&rowbuf[cur ^ 1][0] + k * 1024;
        __builtin_amdgcn_global_load_lds(
            (const __attribute__((address_space(1))) uint32_t*)gp,
            (__attribute__((address_space(3))) uint32_t*)lp, 16, 0, 0);
      }
      diag_next = diagb[(c + 1) * 64 + lane];
    }

    // removed word for this chunk from cross-chunk accumulation
    ull remw = readlane64(rem4, c) | readlane64(rem4, c + 16) |
               readlane64(rem4, c + 32) | readlane64(rem4, c + 48);
    ull chunkmask = (c == 15) ? ((1ull << (KPRE - 15 * 64)) - 1ull) : ~0ull;
    ull alive = ~remw & chunkmask;

    // serial greedy chain — wave-uniform scalar ops + readlane, nothing else
    ull kept = 0;
    while (alive) {
      int ii = __builtin_ctzll(alive);
      kept |= 1ull << ii;
      ull wcur = readlane64(diag, ii);
      alive &= ~(wcur | (1ull << ii));
    }
    if (lane == 0) s_keptw[c] = kept;

    // deferred parallel accumulation: OR all 16 words of kept rows into rem4.
    // lane (q,w) handles rows ii = q + 4*t (static unroll → independent ds_reads)
    #pragma unroll
    for (int t = 0; t < 16; ++t) {
      int ii = q + t * 4;
      ull v = rowbuf[cur][ii * 16 + w];    // always load (pipelined); predicated use
      if ((kept >> ii) & 1ull) rem4 |= v;
    }

    cur ^= 1;
    diag = diag_next;
  }
  __syncthreads();

  // valid mask: kept && score > CONF
  __shared__ ull s_valid[16];
  for (int k = 0; k < 16; ++k) {
    int c = k * 64 + lane;
    bool sv = (c < KPRE) && (s_score[c] > CONF);
    ull m = __ballot(sv) & s_keptw[k];
    if (lane == 0) s_valid[k] = m;
  }
  __syncthreads();

  // prefix counts (valid / invalid among c < KPRE)
  if (lane == 0) {
    int v = 0, iv = 0;
    for (int k = 0; k < 16; ++k) {
      s_vpre[k] = v; s_ipre[k] = iv;
      int nval = (k == 15) ? (KPRE - 15 * 64) : 64;
      int pv = __popcll(s_valid[k]);
      v += pv; iv += nval - pv;
    }
    s_vpre[16] = v; s_ipre[16] = iv;
  }
  __syncthreads();

  // parallel scatter: valid entries in array order, then invalid (tied -1.0)
  int totValid = s_vpre[16];
  for (int k = 0; k < 16; ++k) {
    int c = k * 64 + lane;
    if (c >= KPRE) continue;
    ull wv = s_valid[k];
    ull ltmask = (1ull << lane) - 1ull;
    bool v = (wv >> lane) & 1ull;
    int below = __popcll(wv & ltmask);
    if (v) {
      int rank = s_vpre[k] + below;
      if (rank < MAXDET) { s_sel[rank] = c; s_flag[rank] = 1; }
    } else {
      int rank = totValid + s_ipre[k] + (lane - below);
      if (rank < MAXDET) { s_sel[rank] = c; s_flag[rank] = 0; }
    }
  }
  __syncthreads();

  float* obox = out;                                 // [B][100][4]
  float* osc  = out + (size_t)BATCH * MAXDET * 4;    // [B][100]
  float* ocls = out + (size_t)BATCH * MAXDET * 5;    // [B][100]
  float* odst = out + (size_t)BATCH * MAXDET * 6;    // [B][100][1]
  float* oval = out + (size_t)BATCH * MAXDET * 7;    // [B][100]

  for (int s = lane; s < MAXDET; s += 64) {
    int i = s_sel[s];
    int fl = s_flag[s];
    size_t src = (size_t)b * KPAD + i;
    float4 bx = g_tbox[src];
    float scv = fl ? s_score[i] : -1.0f;
    float clv = (float)g_tcls[src];
    float ddv = g_tdist[src];
    size_t o = (size_t)b * MAXDET + s;
    obox[o * 4 + 0] = bx.x;
    obox[o * 4 + 1] = bx.y;
    obox[o * 4 + 2] = bx.z;
    obox[o * 4 + 3] = bx.w;
    osc[o] = scv;
    ocls[o] = clv;
    odst[o] = ddv;
    oval[o] = fl ? 1.0f : 0.0f;
  }
}

extern "C" void kernel_launch(void* const* d_in, const int* in_sizes, int n_in,
                              void* d_out, int out_size, void* d_ws, size_t ws_size,
                              hipStream_t stream) {
  const float* pboxes = (const float*)d_in[0];   // (32,8400,64)
  const float* pcls   = (const float*)d_in[1];   // (32,8400,80)
  const float* pdist  = (const float*)d_in[2];   // (32,8400,1)
  // d_in[3] = images, unused by the reference computation
  float* out = (float*)d_out;

  char* ws = (char*)d_ws;
  size_t nBN = (size_t)BATCH * NANCH;
  size_t off = 0;
  float*  g_scores = (float*)(ws + off);  off += nBN * 4;
  int*    g_cls    = (int*)(ws + off);    off += nBN * 4;
  float*  g_tscore = (float*)(ws + off);  off += (size_t)BATCH * KPAD * 4;
  float4* g_tbox   = (float4*)(ws + off); off += (size_t)BATCH * KPAD * 16;
  int*    g_tn     = (int*)(ws + off);    off += (size_t)BATCH * KPAD * 4;
  int*    g_tcls   = (int*)(ws + off);    off += (size_t)BATCH * KPAD * 4;
  float*  g_tdist  = (float*)(ws + off);  off += (size_t)BATCH * KPAD * 4;
  ull*    g_sup    = (ull*)(ws + off);    off += (size_t)BATCH * KPAD * 16 * 8;
  ull*    g_diag   = (ull*)(ws + off);    off += (size_t)BATCH * 16 * 64 * 8;

  int total = BATCH * NANCH;
  k_score<<<(total + 255) / 256, 256, 0, stream>>>(pcls, g_scores, g_cls);
  k_topk<<<BATCH, 1024, 0, stream>>>(g_scores, g_cls, pdist,
                                     g_tscore, g_tn, g_tcls, g_tdist);
  k_boxdec<<<(BATCH * KPRE + 255) / 256, 256, 0, stream>>>(pboxes, g_tn, g_tbox);
  dim3 giou(BATCH, 16);
  k_iou<<<giou, 256, 0, stream>>>(g_tbox, g_sup, g_diag);
  k_nms<<<BATCH, 64, 0, stream>>>(g_sup, g_diag, g_tscore, g_tbox, g_tcls, g_tdist, out);
}

// Round 6
// 192.870 us; speedup vs baseline: 1.8012x; 1.0316x over previous
//
#include <hip/hip_runtime.h>
#include <stdint.h>

#define BATCH 32
#define NANCH 8400
#define NCLS 80
#define KPRE 1000
#define KPAD 1024
#define MAXDET 100
#define CONF 0.2f
#define IOUTHR 0.7f

typedef unsigned long long ull;

// monotonic map: float -> uint32 preserving total order
__device__ __forceinline__ uint32_t fmap(float f) {
  uint32_t u = __float_as_uint(f);
  return (u & 0x80000000u) ? ~u : (u | 0x80000000u);
}

__device__ __forceinline__ ull readlane64(ull v, int lane) {
  uint32_t lo = __builtin_amdgcn_readlane((uint32_t)(v & 0xffffffffull), lane);
  uint32_t hi = __builtin_amdgcn_readlane((uint32_t)(v >> 32), lane);
  return ((ull)hi << 32) | (ull)lo;
}

// ---------------- Kernel 1: class score max/argmax only ----------------
__global__ __launch_bounds__(256) void k_score(
    const float* __restrict__ pcls,     // [B][N][80]
    float* __restrict__ g_scores,       // [B][N]
    int* __restrict__ g_cls)            // [B][N]
{
  int gid = blockIdx.x * blockDim.x + threadIdx.x;
  if (gid >= BATCH * NANCH) return;

  // class max / argmax (first occurrence wins: strict >)
  const float4* pc = (const float4*)(pcls + (size_t)gid * NCLS);
  float best = -3.402823466e38f;
  int bidx = 0;
  #pragma unroll
  for (int k = 0; k < NCLS / 4; ++k) {
    float4 v = pc[k];
    if (v.x > best) { best = v.x; bidx = 4 * k + 0; }
    if (v.y > best) { best = v.y; bidx = 4 * k + 1; }
    if (v.z > best) { best = v.z; bidx = 4 * k + 2; }
    if (v.w > best) { best = v.w; bidx = 4 * k + 3; }
  }
  g_scores[gid] = best;
  g_cls[gid] = bidx;
}

// ---------------- Kernel 2: exact stable top-1000 + DFL box decode ----------------
// composite 46-bit key: (fmap(score) << 14) | (NANCH-1-i). All keys distinct.
#define NITER2 23   // 2 bits per round: 4^23 = 2^46
#define NQ 9        // ceil(8400/1024)

__global__ __launch_bounds__(1024) void k_topk(
    const float* __restrict__ g_scores,
    const int* __restrict__ g_cls,
    const float* __restrict__ g_dist_in,   // [B][N][1]
    const float* __restrict__ pboxes,      // [B][N][64]
    float* __restrict__ g_tscore,          // [B][KPAD]
    float4* __restrict__ g_tbox,           // [B][KPAD]
    int* __restrict__ g_tcls,              // [B][KPAD]
    float* __restrict__ g_tdist)           // [B][KPAD]
{
  int b = blockIdx.x;
  int tid = threadIdx.x;
  int lane = tid & 63;
  __shared__ float ls[NANCH];
  __shared__ ull skeys[KPAD];
  __shared__ ull s_cnt[NITER2];
  __shared__ int s_pos;

  const float* sc = g_scores + (size_t)b * NANCH;

  // load scores to LDS + build per-thread keys in registers (static indexing)
  ull key[NQ];
  #pragma unroll
  for (int q = 0; q < NQ; ++q) {
    int i = tid + q * 1024;
    if (i < NANCH) {
      float x = sc[i];
      ls[i] = x;
      key[q] = ((ull)fmap(x) << 14) | (ull)(uint32_t)(NANCH - 1 - i);
    } else {
      key[q] = 0ull;  // never selected (thresholds always > 0; real keys >= 2^45)
    }
  }
  if (tid < NITER2) s_cnt[tid] = 0ull;
  if (tid == 0) s_pos = 0;
  __syncthreads();

  // 4-way bisection for exact 1000th-largest key: 23 rounds, 1 barrier each.
  // c1,c2,c3 packed into one u64 (21-bit fields; block totals <= 9216 < 2^21)
  ull lo = 0, width = 1ull << 46;
  for (int it = 0; it < NITER2; ++it) {
    ull d = width >> 2;
    ull t1 = lo + d, t2 = lo + 2 * d, t3 = lo + 3 * d;
    int c1 = 0, c2 = 0, c3 = 0;
    #pragma unroll
    for (int q = 0; q < NQ; ++q) {
      ull k = key[q];
      c1 += (k >= t1) ? 1 : 0;
      c2 += (k >= t2) ? 1 : 0;
      c3 += (k >= t3) ? 1 : 0;
    }
    ull pk = (ull)c1 | ((ull)c2 << 21) | ((ull)c3 << 42);
    #pragma unroll
    for (int off = 32; off > 0; off >>= 1) pk += __shfl_down(pk, off);
    if (lane == 0) atomicAdd(&s_cnt[it], pk);
    __syncthreads();
    ull t = s_cnt[it];
    int C1 = (int)(t & 0x1FFFFFull);
    int C2 = (int)((t >> 21) & 0x1FFFFFull);
    int C3 = (int)(t >> 42);
    if (C3 >= KPRE)      lo = t3;
    else if (C2 >= KPRE) lo = t2;
    else if (C1 >= KPRE) lo = t1;
    width = d;
  }
  // lo == exact 1000th largest key; exactly KPRE keys >= lo

  // compact selected keys to LDS (order irrelevant; sorted next)
  #pragma unroll
  for (int q = 0; q < NQ; ++q) {
    bool sel = (key[q] >= lo);
    ull m = __ballot(sel);
    int base = 0;
    if (lane == 0) base = atomicAdd(&s_pos, __popcll(m));
    base = __shfl(base, 0);
    if (sel) skeys[base + __popcll(m & ((1ull << lane) - 1ull))] = key[q];
  }
  if (tid >= KPRE) skeys[tid] = 0ull;  // pad sorts last
  __syncthreads();

  // bitonic sort 1024 keys descending — keys in registers;
  // j<=32 phases via shfl_xor (barrier-free), j>=64 via LDS exchange
  ull K = skeys[tid];
  for (int k = 2; k <= KPAD; k <<= 1) {
    bool descDir = ((tid & k) == 0);
    for (int j = k >> 1; j > 0; j >>= 1) {
      ull P;
      if (j >= 64) {
        __syncthreads();           // prior reads of skeys done
        skeys[tid] = K;
        __syncthreads();
        P = skeys[tid ^ j];
      } else {
        P = __shfl_xor(K, j);
      }
      bool iAmLow = (tid & j) == 0;
      bool takeMax = (iAmLow == descDir);
      bool pGreater = P > K;
      if (takeMax == pGreater) K = P;
    }
  }

  if (tid < KPRE) {
    int n = (NANCH - 1) - (int)(uint32_t)(K & 0x3FFFull);
    size_t src = (size_t)b * NANCH + n;
    size_t dst = (size_t)b * KPAD + tid;
    g_tscore[dst] = ls[n];
    g_tcls[dst] = g_cls[src];
    g_tdist[dst] = g_dist_in[src];

    // DFL: softmax over 16 then dot with arange(16), matching JAX order
    const float4* pb = (const float4*)(pboxes + src * 64);
    float dist[4];
    #pragma unroll
    for (int k = 0; k < 4; ++k) {
      float v[16];
      #pragma unroll
      for (int q = 0; q < 4; ++q) {
        float4 t = pb[k * 4 + q];
        v[q * 4 + 0] = t.x; v[q * 4 + 1] = t.y; v[q * 4 + 2] = t.z; v[q * 4 + 3] = t.w;
      }
      float m = v[0];
      #pragma unroll
      for (int r = 1; r < 16; ++r) m = fmaxf(m, v[r]);
      float e[16];
      float su = 0.f;
      #pragma unroll
      for (int r = 0; r < 16; ++r) { e[r] = expf(v[r] - m); su += e[r]; }
      float acc = 0.f;
      #pragma unroll
      for (int r = 0; r < 16; ++r) acc += (e[r] / su) * (float)r;
      dist[k] = acc;
    }

    int n0, W; float sf;
    if (n < 6400)      { n0 = n;        W = 80; sf = 8.f;  }
    else if (n < 8000) { n0 = n - 6400; W = 40; sf = 16.f; }
    else               { n0 = n - 8000; W = 20; sf = 32.f; }
    float ax = (float)(n0 % W) + 0.5f;
    float ay = (float)(n0 / W) + 0.5f;

    float4 bx;
    bx.x = (ax - dist[0]) * sf;
    bx.y = (ay - dist[1]) * sf;
    bx.z = (ax + dist[2]) * sf;
    bx.w = (ay + dist[3]) * sf;
    g_tbox[dst] = bx;
  }
}

// ---------------- Kernel 3: suppression bit-matrix (1 word per wave-task) ----------------
__global__ __launch_bounds__(256) void k_iou(
    const float4* __restrict__ g_tbox,
    ull* __restrict__ g_sup,              // [B][KPAD][16] row-major
    ull* __restrict__ g_diag)             // [B][16][64] diag blocks
{
  int b = blockIdx.x;
  int c = blockIdx.y;            // row-chunk: rows [c*64, c*64+64)
  int tid = threadIdx.x;
  int wave = tid >> 6;           // 4 waves/block
  int lane = tid & 63;
  __shared__ float4 s_box[KPRE];
  __shared__ float s_area[KPRE];
  for (int t = tid; t < KPRE; t += 256) {
    float4 v = g_tbox[(size_t)b * KPAD + t];
    s_box[t] = v;
    s_area[t] = (v.z - v.x) * (v.w - v.y);
  }
  __syncthreads();

  // 64 rows x 16 words = 1024 wave-tasks, strided over 4 waves
  for (int task = wave; task < 64 * 16; task += 4) {
    int r = task >> 4;
    int w = task & 15;
    int i = c * 64 + r;
    if (i >= KPRE) continue;               // wave-uniform
    ull word = 0;
    if (w * 64 + 63 > i) {                 // word intersects upper triangle
      int j = w * 64 + lane;
      bool p = false;
      if (j > i && j < KPRE) {
        float4 bi = s_box[i];              // broadcast
        float4 bj = s_box[j];
        float ltx = fmaxf(bi.x, bj.x);
        float lty = fmaxf(bi.y, bj.y);
        float rbx = fminf(bi.z, bj.z);
        float rby = fminf(bi.w, bj.w);
        float wx = fmaxf(rbx - ltx, 0.f);
        float wy = fmaxf(rby - lty, 0.f);
        float inter = wx * wy;
        float den = ((s_area[i] + s_area[j]) - inter) + 1e-7f;
        p = (inter / den) > IOUTHR;
      }
      word = __ballot(p);
    }
    if (lane == 0) {
      g_sup[((size_t)b * KPAD + i) * 16 + w] = word;
      if (w == c) g_diag[((size_t)b * 16 + c) * 64 + r] = word;
    }
  }
}

// ---------------- Kernel 4: scalar-chain NMS + parallel selection + output ----------------
__global__ __launch_bounds__(64) void k_nms(
    const ull* __restrict__ g_sup,
    const ull* __restrict__ g_diag,
    const float* __restrict__ g_tscore,
    const float4* __restrict__ g_tbox,
    const int* __restrict__ g_tcls,
    const float* __restrict__ g_tdist,
    float* __restrict__ out)
{
  int b = blockIdx.x;
  int lane = threadIdx.x;
  __shared__ __align__(16) ull rowbuf[2][64 * 16];   // 16 KB double buffer
  __shared__ float s_score[KPAD];
  __shared__ ull s_keptw[16];
  __shared__ int s_vpre[17];
  __shared__ int s_ipre[17];
  __shared__ int s_sel[MAXDET];
  __shared__ int s_flag[MAXDET];

  for (int t = lane; t < KPAD; t += 64)
    s_score[t] = g_tscore[(size_t)b * KPAD + t];

  const char* supb = (const char*)(g_sup + (size_t)b * KPAD * 16);
  const ull* diagb = g_diag + (size_t)b * 16 * 64;

  // prefetch chunk 0 (8 KB) into rowbuf[0] via global_load_lds width-16
  #pragma unroll
  for (int k = 0; k < 8; ++k) {
    const void* gp = supb + (size_t)k * 1024 + (size_t)lane * 16;
    void* lp = (char*)&rowbuf[0][0] + k * 1024;
    __builtin_amdgcn_global_load_lds(
        (const __attribute__((address_space(1))) uint32_t*)gp,
        (__attribute__((address_space(3))) uint32_t*)lp, 16, 0, 0);
  }
  ull diag = diagb[0 * 64 + lane];   // diag words for chunk 0

  // rem4: lane (q=lane>>4, w=lane&15) accumulates word w over kept rows ii with (ii&3)==q
  ull rem4 = 0;
  int w = lane & 15;
  int q = lane >> 4;
  int cur = 0;

  for (int c = 0; c < 16; ++c) {
    asm volatile("s_waitcnt vmcnt(0)" ::: "memory");  // chunk c staged, diag ready

    ull diag_next = 0;
    if (c < 15) {
      #pragma unroll
      for (int k = 0; k < 8; ++k) {
        const void* gp = supb + (size_t)(c + 1) * 8192 + (size_t)k * 1024 + (size_t)lane * 16;
        void* lp = (char*)&rowbuf[cur ^ 1][0] + k * 1024;
        __builtin_amdgcn_global_load_lds(
            (const __attribute__((address_space(1))) uint32_t*)gp,
            (__attribute__((address_space(3))) uint32_t*)lp, 16, 0, 0);
      }
      diag_next = diagb[(c + 1) * 64 + lane];
    }

    // removed word for this chunk from cross-chunk accumulation
    ull remw = readlane64(rem4, c) | readlane64(rem4, c + 16) |
               readlane64(rem4, c + 32) | readlane64(rem4, c + 48);
    ull chunkmask = (c == 15) ? ((1ull << (KPRE - 15 * 64)) - 1ull) : ~0ull;
    ull alive = ~remw & chunkmask;

    // serial greedy chain — wave-uniform scalar ops + readlane, nothing else
    ull kept = 0;
    while (alive) {
      int ii = __builtin_ctzll(alive);
      kept |= 1ull << ii;
      ull wcur = readlane64(diag, ii);
      alive &= ~(wcur | (1ull << ii));
    }
    if (lane == 0) s_keptw[c] = kept;

    // deferred parallel accumulation: OR all 16 words of kept rows into rem4.
    #pragma unroll
    for (int t = 0; t < 16; ++t) {
      int ii = q + t * 4;
      ull v = rowbuf[cur][ii * 16 + w];    // always load (pipelined); predicated use
      if ((kept >> ii) & 1ull) rem4 |= v;
    }

    cur ^= 1;
    diag = diag_next;
  }
  __syncthreads();

  // valid mask: kept && score > CONF
  __shared__ ull s_valid[16];
  for (int k = 0; k < 16; ++k) {
    int c = k * 64 + lane;
    bool sv = (c < KPRE) && (s_score[c] > CONF);
    ull m = __ballot(sv) & s_keptw[k];
    if (lane == 0) s_valid[k] = m;
  }
  __syncthreads();

  // prefix counts (valid / invalid among c < KPRE)
  if (lane == 0) {
    int v = 0, iv = 0;
    for (int k = 0; k < 16; ++k) {
      s_vpre[k] = v; s_ipre[k] = iv;
      int nval = (k == 15) ? (KPRE - 15 * 64) : 64;
      int pv = __popcll(s_valid[k]);
      v += pv; iv += nval - pv;
    }
    s_vpre[16] = v; s_ipre[16] = iv;
  }
  __syncthreads();

  // parallel scatter: valid entries in array order, then invalid (tied -1.0)
  int totValid = s_vpre[16];
  for (int k = 0; k < 16; ++k) {
    int c = k * 64 + lane;
    if (c >= KPRE) continue;
    ull wv = s_valid[k];
    ull ltmask = (1ull << lane) - 1ull;
    bool v = (wv >> lane) & 1ull;
    int below = __popcll(wv & ltmask);
    if (v) {
      int rank = s_vpre[k] + below;
      if (rank < MAXDET) { s_sel[rank] = c; s_flag[rank] = 1; }
    } else {
      int rank = totValid + s_ipre[k] + (lane - below);
      if (rank < MAXDET) { s_sel[rank] = c; s_flag[rank] = 0; }
    }
  }
  __syncthreads();

  float* obox = out;                                 // [B][100][4]
  float* osc  = out + (size_t)BATCH * MAXDET * 4;    // [B][100]
  float* ocls = out + (size_t)BATCH * MAXDET * 5;    // [B][100]
  float* odst = out + (size_t)BATCH * MAXDET * 6;    // [B][100][1]
  float* oval = out + (size_t)BATCH * MAXDET * 7;    // [B][100]

  for (int s = lane; s < MAXDET; s += 64) {
    int i = s_sel[s];
    int fl = s_flag[s];
    size_t src = (size_t)b * KPAD + i;
    float4 bx = g_tbox[src];
    float scv = fl ? s_score[i] : -1.0f;
    float clv = (float)g_tcls[src];
    float ddv = g_tdist[src];
    size_t o = (size_t)b * MAXDET + s;
    obox[o * 4 + 0] = bx.x;
    obox[o * 4 + 1] = bx.y;
    obox[o * 4 + 2] = bx.z;
    obox[o * 4 + 3] = bx.w;
    osc[o] = scv;
    ocls[o] = clv;
    odst[o] = ddv;
    oval[o] = fl ? 1.0f : 0.0f;
  }
}

extern "C" void kernel_launch(void* const* d_in, const int* in_sizes, int n_in,
                              void* d_out, int out_size, void* d_ws, size_t ws_size,
                              hipStream_t stream) {
  const float* pboxes = (const float*)d_in[0];   // (32,8400,64)
  const float* pcls   = (const float*)d_in[1];   // (32,8400,80)
  const float* pdist  = (const float*)d_in[2];   // (32,8400,1)
  // d_in[3] = images, unused by the reference computation
  float* out = (float*)d_out;

  char* ws = (char*)d_ws;
  size_t nBN = (size_t)BATCH * NANCH;
  size_t off = 0;
  float*  g_scores = (float*)(ws + off);  off += nBN * 4;
  int*    g_cls    = (int*)(ws + off);    off += nBN * 4;
  float*  g_tscore = (float*)(ws + off);  off += (size_t)BATCH * KPAD * 4;
  float4* g_tbox   = (float4*)(ws + off); off += (size_t)BATCH * KPAD * 16;
  int*    g_tcls   = (int*)(ws + off);    off += (size_t)BATCH * KPAD * 4;
  float*  g_tdist  = (float*)(ws + off);  off += (size_t)BATCH * KPAD * 4;
  ull*    g_sup    = (ull*)(ws + off);    off += (size_t)BATCH * KPAD * 16 * 8;
  ull*    g_diag   = (ull*)(ws + off);    off += (size_t)BATCH * 16 * 64 * 8;

  int total = BATCH * NANCH;
  k_score<<<(total + 255) / 256, 256, 0, stream>>>(pcls, g_scores, g_cls);
  k_topk<<<BATCH, 1024, 0, stream>>>(g_scores, g_cls, pdist, pboxes,
                                     g_tscore, g_tbox, g_tcls, g_tdist);
  dim3 giou(BATCH, 16);
  k_iou<<<giou, 256, 0, stream>>>(g_tbox, g_sup, g_diag);
  k_nms<<<BATCH, 64, 0, stream>>>(g_sup, g_diag, g_tscore, g_tbox, g_tcls, g_tdist, out);
}

// Round 7
// 184.254 us; speedup vs baseline: 1.8854x; 1.0468x over previous
//
#include <hip/hip_runtime.h>
#include <stdint.h>

#define BATCH 32
#define NANCH 8400
#define NCLS 80
#define KPRE 1000
#define KPAD 1024
#define MAXDET 100
#define CONF 0.2f
#define IOUTHR 0.7f

typedef unsigned long long ull;

// monotonic map: float -> uint32 preserving total order
__device__ __forceinline__ uint32_t fmap(float f) {
  uint32_t u = __float_as_uint(f);
  return (u & 0x80000000u) ? ~u : (u | 0x80000000u);
}

__device__ __forceinline__ ull readlane64(ull v, int lane) {
  uint32_t lo = __builtin_amdgcn_readlane((uint32_t)(v & 0xffffffffull), lane);
  uint32_t hi = __builtin_amdgcn_readlane((uint32_t)(v >> 32), lane);
  return ((ull)hi << 32) | (ull)lo;
}

// ---------------- Kernel 1: class score max/argmax, 4 lanes per row ----------------
__global__ __launch_bounds__(256) void k_score(
    const float* __restrict__ pcls,     // [B][N][80]
    float* __restrict__ g_scores,       // [B][N]
    int* __restrict__ g_cls)            // [B][N]
{
  int g4 = blockIdx.x * blockDim.x + threadIdx.x;
  if (g4 >= BATCH * NANCH * 4) return;
  int row = g4 >> 2;
  int part = g4 & 3;   // 20 classes per part

  const float4* pc = (const float4*)(pcls + (size_t)row * NCLS) + part * 5;
  float best = -3.402823466e38f;
  int bidx = 0;
  #pragma unroll
  for (int k = 0; k < 5; ++k) {
    float4 v = pc[k];
    int base = part * 20 + 4 * k;
    if (v.x > best) { best = v.x; bidx = base + 0; }
    if (v.y > best) { best = v.y; bidx = base + 1; }
    if (v.z > best) { best = v.z; bidx = base + 2; }
    if (v.w > best) { best = v.w; bidx = base + 3; }
  }
  // reduce across the 4-lane group; exact first-occurrence tie rule
  #pragma unroll
  for (int d = 1; d <= 2; d <<= 1) {
    float ob = __shfl_xor(best, d);
    int oi = __shfl_xor(bidx, d);
    if (ob > best || (ob == best && oi < bidx)) { best = ob; bidx = oi; }
  }
  if (part == 0) {
    g_scores[row] = best;
    g_cls[row] = bidx;
  }
}

// ---------------- Kernel 2: exact stable top-1000 per batch ----------------
// composite 46-bit key: (fmap(score) << 14) | (NANCH-1-i). All keys distinct.
#define NITER2 23   // 2 bits per round: 4^23 = 2^46
#define NQ 9        // ceil(8400/1024)

__global__ __launch_bounds__(1024) void k_topk(
    const float* __restrict__ g_scores,
    const int* __restrict__ g_cls,
    const float* __restrict__ g_dist_in,   // [B][N][1]
    float* __restrict__ g_tscore,          // [B][KPAD]
    int* __restrict__ g_tn,                // [B][KPAD] selected anchor index
    int* __restrict__ g_tcls,              // [B][KPAD]
    float* __restrict__ g_tdist)           // [B][KPAD]
{
  int b = blockIdx.x;
  int tid = threadIdx.x;
  int lane = tid & 63;
  __shared__ float ls[NANCH];
  __shared__ ull skeys[KPAD];
  __shared__ ull s_cnt[NITER2];
  __shared__ int s_pos;

  const float* sc = g_scores + (size_t)b * NANCH;

  // load scores to LDS + build per-thread keys in registers (static indexing)
  ull key[NQ];
  #pragma unroll
  for (int q = 0; q < NQ; ++q) {
    int i = tid + q * 1024;
    if (i < NANCH) {
      float x = sc[i];
      ls[i] = x;
      key[q] = ((ull)fmap(x) << 14) | (ull)(uint32_t)(NANCH - 1 - i);
    } else {
      key[q] = 0ull;  // never selected (thresholds always > 0; real keys >= 2^45)
    }
  }
  if (tid < NITER2) s_cnt[tid] = 0ull;
  if (tid == 0) s_pos = 0;
  __syncthreads();

  // 4-way bisection for exact 1000th-largest key: 23 rounds, 1 barrier each.
  // c1,c2,c3 packed into one u64 (21-bit fields; block totals <= 9216 < 2^21)
  ull lo = 0, width = 1ull << 46;
  for (int it = 0; it < NITER2; ++it) {
    ull d = width >> 2;
    ull t1 = lo + d, t2 = lo + 2 * d, t3 = lo + 3 * d;
    int c1 = 0, c2 = 0, c3 = 0;
    #pragma unroll
    for (int q = 0; q < NQ; ++q) {
      ull k = key[q];
      c1 += (k >= t1) ? 1 : 0;
      c2 += (k >= t2) ? 1 : 0;
      c3 += (k >= t3) ? 1 : 0;
    }
    ull pk = (ull)c1 | ((ull)c2 << 21) | ((ull)c3 << 42);
    #pragma unroll
    for (int off = 32; off > 0; off >>= 1) pk += __shfl_down(pk, off);
    if (lane == 0) atomicAdd(&s_cnt[it], pk);
    __syncthreads();
    ull t = s_cnt[it];
    int C1 = (int)(t & 0x1FFFFFull);
    int C2 = (int)((t >> 21) & 0x1FFFFFull);
    int C3 = (int)(t >> 42);
    if (C3 >= KPRE)      lo = t3;
    else if (C2 >= KPRE) lo = t2;
    else if (C1 >= KPRE) lo = t1;
    width = d;
  }
  // lo == exact 1000th largest key; exactly KPRE keys >= lo

  // compact selected keys to LDS (order irrelevant; sorted next)
  #pragma unroll
  for (int q = 0; q < NQ; ++q) {
    bool sel = (key[q] >= lo);
    ull m = __ballot(sel);
    int base = 0;
    if (lane == 0) base = atomicAdd(&s_pos, __popcll(m));
    base = __shfl(base, 0);
    if (sel) skeys[base + __popcll(m & ((1ull << lane) - 1ull))] = key[q];
  }
  if (tid >= KPRE) skeys[tid] = 0ull;  // pad sorts last
  __syncthreads();

  // bitonic sort 1024 keys descending — keys in registers;
  // j<=32 phases via shfl_xor (barrier-free), j>=64 via LDS exchange
  ull K = skeys[tid];
  for (int k = 2; k <= KPAD; k <<= 1) {
    bool descDir = ((tid & k) == 0);
    for (int j = k >> 1; j > 0; j >>= 1) {
      ull P;
      if (j >= 64) {
        __syncthreads();           // prior reads of skeys done
        skeys[tid] = K;
        __syncthreads();
        P = skeys[tid ^ j];
      } else {
        P = __shfl_xor(K, j);
      }
      bool iAmLow = (tid & j) == 0;
      bool takeMax = (iAmLow == descDir);
      bool pGreater = P > K;
      if (takeMax == pGreater) K = P;
    }
  }

  if (tid < KPRE) {
    int n = (NANCH - 1) - (int)(uint32_t)(K & 0x3FFFull);
    size_t src = (size_t)b * NANCH + n;
    size_t dst = (size_t)b * KPAD + tid;
    g_tscore[dst] = ls[n];
    g_tn[dst] = n;
    g_tcls[dst] = g_cls[src];
    g_tdist[dst] = g_dist_in[src];
  }
}

// ---------------- Kernel 2b: DFL box decode for selected anchors only ----------------
__global__ __launch_bounds__(256) void k_boxdec(
    const float* __restrict__ pboxes,   // [B][N][64]
    const int* __restrict__ g_tn,       // [B][KPAD]
    float4* __restrict__ g_tbox)        // [B][KPAD]
{
  int gid = blockIdx.x * blockDim.x + threadIdx.x;
  if (gid >= BATCH * KPRE) return;
  int b = gid / KPRE;
  int s = gid % KPRE;
  int n = g_tn[(size_t)b * KPAD + s];

  // DFL: softmax over 16 then dot with arange(16), matching JAX order
  const float4* pb = (const float4*)(pboxes + ((size_t)b * NANCH + n) * 64);
  float dist[4];
  #pragma unroll
  for (int k = 0; k < 4; ++k) {
    float v[16];
    #pragma unroll
    for (int q = 0; q < 4; ++q) {
      float4 t = pb[k * 4 + q];
      v[q * 4 + 0] = t.x; v[q * 4 + 1] = t.y; v[q * 4 + 2] = t.z; v[q * 4 + 3] = t.w;
    }
    float m = v[0];
    #pragma unroll
    for (int r = 1; r < 16; ++r) m = fmaxf(m, v[r]);
    float e[16];
    float su = 0.f;
    #pragma unroll
    for (int r = 0; r < 16; ++r) { e[r] = expf(v[r] - m); su += e[r]; }
    float acc = 0.f;
    #pragma unroll
    for (int r = 0; r < 16; ++r) acc += (e[r] / su) * (float)r;
    dist[k] = acc;
  }

  // anchors: levels 80x80(s8), 40x40(s16), 20x20(s32); anchor=(col+0.5, row+0.5)
  int n0, W; float sf;
  if (n < 6400)      { n0 = n;        W = 80; sf = 8.f;  }
  else if (n < 8000) { n0 = n - 6400; W = 40; sf = 16.f; }
  else               { n0 = n - 8000; W = 20; sf = 32.f; }
  float ax = (float)(n0 % W) + 0.5f;
  float ay = (float)(n0 / W) + 0.5f;

  float4 bx;
  bx.x = (ax - dist[0]) * sf;
  bx.y = (ay - dist[1]) * sf;
  bx.z = (ax + dist[2]) * sf;
  bx.w = (ay + dist[3]) * sf;

  g_tbox[(size_t)b * KPAD + s] = bx;
}

// ---------------- Kernel 3: suppression bit-matrix (1 word per wave-task) ----------------
__global__ __launch_bounds__(256) void k_iou(
    const float4* __restrict__ g_tbox,
    ull* __restrict__ g_sup,              // [B][KPAD][16] row-major
    ull* __restrict__ g_diag)             // [B][16][64] diag blocks
{
  int b = blockIdx.x;
  int c = blockIdx.y;            // row-chunk: rows [c*64, c*64+64)
  int tid = threadIdx.x;
  int wave = tid >> 6;           // 4 waves/block
  int lane = tid & 63;
  __shared__ float4 s_box[KPRE];
  __shared__ float s_area[KPRE];
  for (int t = tid; t < KPRE; t += 256) {
    float4 v = g_tbox[(size_t)b * KPAD + t];
    s_box[t] = v;
    s_area[t] = (v.z - v.x) * (v.w - v.y);
  }
  __syncthreads();

  // 64 rows x 16 words = 1024 wave-tasks, strided over 4 waves
  for (int task = wave; task < 64 * 16; task += 4) {
    int r = task >> 4;
    int w = task & 15;
    int i = c * 64 + r;
    if (i >= KPRE) continue;               // wave-uniform
    ull word = 0;
    if (w * 64 + 63 > i) {                 // word intersects upper triangle
      int j = w * 64 + lane;
      bool p = false;
      if (j > i && j < KPRE) {
        float4 bi = s_box[i];              // broadcast
        float4 bj = s_box[j];
        float ltx = fmaxf(bi.x, bj.x);
        float lty = fmaxf(bi.y, bj.y);
        float rbx = fminf(bi.z, bj.z);
        float rby = fminf(bi.w, bj.w);
        float wx = fmaxf(rbx - ltx, 0.f);
        float wy = fmaxf(rby - lty, 0.f);
        float inter = wx * wy;
        float den = ((s_area[i] + s_area[j]) - inter) + 1e-7f;
        p = (inter / den) > IOUTHR;
      }
      word = __ballot(p);
    }
    if (lane == 0) {
      g_sup[((size_t)b * KPAD + i) * 16 + w] = word;
      if (w == c) g_diag[((size_t)b * 16 + c) * 64 + r] = word;
    }
  }
}

// ---------------- Kernel 4: scalar-chain NMS + parallel selection + output ----------------
__global__ __launch_bounds__(64) void k_nms(
    const ull* __restrict__ g_sup,
    const ull* __restrict__ g_diag,
    const float* __restrict__ g_tscore,
    const float4* __restrict__ g_tbox,
    const int* __restrict__ g_tcls,
    const float* __restrict__ g_tdist,
    float* __restrict__ out)
{
  int b = blockIdx.x;
  int lane = threadIdx.x;
  __shared__ __align__(16) ull rowbuf[2][64 * 16];   // 16 KB double buffer
  __shared__ float s_score[KPAD];
  __shared__ ull s_keptw[16];
  __shared__ int s_vpre[17];
  __shared__ int s_ipre[17];
  __shared__ int s_sel[MAXDET];
  __shared__ int s_flag[MAXDET];

  for (int t = lane; t < KPAD; t += 64)
    s_score[t] = g_tscore[(size_t)b * KPAD + t];

  const char* supb = (const char*)(g_sup + (size_t)b * KPAD * 16);
  const ull* diagb = g_diag + (size_t)b * 16 * 64;

  // prefetch chunk 0 (8 KB) into rowbuf[0] via global_load_lds width-16
  #pragma unroll
  for (int k = 0; k < 8; ++k) {
    const void* gp = supb + (size_t)k * 1024 + (size_t)lane * 16;
    void* lp = (char*)&rowbuf[0][0] + k * 1024;
    __builtin_amdgcn_global_load_lds(
        (const __attribute__((address_space(1))) uint32_t*)gp,
        (__attribute__((address_space(3))) uint32_t*)lp, 16, 0, 0);
  }
  ull diag = diagb[0 * 64 + lane];   // diag words for chunk 0

  // rem4: lane (q=lane>>4, w=lane&15) accumulates word w over kept rows ii with (ii&3)==q
  ull rem4 = 0;
  int w = lane & 15;
  int q = lane >> 4;
  int cur = 0;

  for (int c = 0; c < 16; ++c) {
    asm volatile("s_waitcnt vmcnt(0)" ::: "memory");  // chunk c staged, diag ready

    ull diag_next = 0;
    if (c < 15) {
      #pragma unroll
      for (int k = 0; k < 8; ++k) {
        const void* gp = supb + (size_t)(c + 1) * 8192 + (size_t)k * 1024 + (size_t)lane * 16;
        void* lp = (char*)&rowbuf[cur ^ 1][0] + k * 1024;
        __builtin_amdgcn_global_load_lds(
            (const __attribute__((address_space(1))) uint32_t*)gp,
            (__attribute__((address_space(3))) uint32_t*)lp, 16, 0, 0);
      }
      diag_next = diagb[(c + 1) * 64 + lane];
    }

    // removed word for this chunk from cross-chunk accumulation
    ull remw = readlane64(rem4, c) | readlane64(rem4, c + 16) |
               readlane64(rem4, c + 32) | readlane64(rem4, c + 48);
    ull chunkmask = (c == 15) ? ((1ull << (KPRE - 15 * 64)) - 1ull) : ~0ull;
    ull alive = ~remw & chunkmask;

    // serial greedy chain — wave-uniform scalar ops + readlane, nothing else
    ull kept = 0;
    while (alive) {
      int ii = __builtin_ctzll(alive);
      kept |= 1ull << ii;
      ull wcur = readlane64(diag, ii);
      alive &= ~(wcur | (1ull << ii));
    }
    if (lane == 0) s_keptw[c] = kept;

    // deferred parallel accumulation: OR all 16 words of kept rows into rem4.
    #pragma unroll
    for (int t = 0; t < 16; ++t) {
      int ii = q + t * 4;
      ull v = rowbuf[cur][ii * 16 + w];    // always load (pipelined); predicated use
      if ((kept >> ii) & 1ull) rem4 |= v;
    }

    cur ^= 1;
    diag = diag_next;
  }
  __syncthreads();

  // valid mask: kept && score > CONF
  __shared__ ull s_valid[16];
  for (int k = 0; k < 16; ++k) {
    int c = k * 64 + lane;
    bool sv = (c < KPRE) && (s_score[c] > CONF);
    ull m = __ballot(sv) & s_keptw[k];
    if (lane == 0) s_valid[k] = m;
  }
  __syncthreads();

  // prefix counts (valid / invalid among c < KPRE)
  if (lane == 0) {
    int v = 0, iv = 0;
    for (int k = 0; k < 16; ++k) {
      s_vpre[k] = v; s_ipre[k] = iv;
      int nval = (k == 15) ? (KPRE - 15 * 64) : 64;
      int pv = __popcll(s_valid[k]);
      v += pv; iv += nval - pv;
    }
    s_vpre[16] = v; s_ipre[16] = iv;
  }
  __syncthreads();

  // parallel scatter: valid entries in array order, then invalid (tied -1.0)
  int totValid = s_vpre[16];
  for (int k = 0; k < 16; ++k) {
    int c = k * 64 + lane;
    if (c >= KPRE) continue;
    ull wv = s_valid[k];
    ull ltmask = (1ull << lane) - 1ull;
    bool v = (wv >> lane) & 1ull;
    int below = __popcll(wv & ltmask);
    if (v) {
      int rank = s_vpre[k] + below;
      if (rank < MAXDET) { s_sel[rank] = c; s_flag[rank] = 1; }
    } else {
      int rank = totValid + s_ipre[k] + (lane - below);
      if (rank < MAXDET) { s_sel[rank] = c; s_flag[rank] = 0; }
    }
  }
  __syncthreads();

  float* obox = out;                                 // [B][100][4]
  float* osc  = out + (size_t)BATCH * MAXDET * 4;    // [B][100]
  float* ocls = out + (size_t)BATCH * MAXDET * 5;    // [B][100]
  float* odst = out + (size_t)BATCH * MAXDET * 6;    // [B][100][1]
  float* oval = out + (size_t)BATCH * MAXDET * 7;    // [B][100]

  for (int s = lane; s < MAXDET; s += 64) {
    int i = s_sel[s];
    int fl = s_flag[s];
    size_t src = (size_t)b * KPAD + i;
    float4 bx = g_tbox[src];
    float scv = fl ? s_score[i] : -1.0f;
    float clv = (float)g_tcls[src];
    float ddv = g_tdist[src];
    size_t o = (size_t)b * MAXDET + s;
    obox[o * 4 + 0] = bx.x;
    obox[o * 4 + 1] = bx.y;
    obox[o * 4 + 2] = bx.z;
    obox[o * 4 + 3] = bx.w;
    osc[o] = scv;
    ocls[o] = clv;
    odst[o] = ddv;
    oval[o] = fl ? 1.0f : 0.0f;
  }
}

extern "C" void kernel_launch(void* const* d_in, const int* in_sizes, int n_in,
                              void* d_out, int out_size, void* d_ws, size_t ws_size,
                              hipStream_t stream) {
  const float* pboxes = (const float*)d_in[0];   // (32,8400,64)
  const float* pcls   = (const float*)d_in[1];   // (32,8400,80)
  const float* pdist  = (const float*)d_in[2];   // (32,8400,1)
  // d_in[3] = images, unused by the reference computation
  float* out = (float*)d_out;

  char* ws = (char*)d_ws;
  size_t nBN = (size_t)BATCH * NANCH;
  size_t off = 0;
  float*  g_scores = (float*)(ws + off);  off += nBN * 4;
  int*    g_cls    = (int*)(ws + off);    off += nBN * 4;
  float*  g_tscore = (float*)(ws + off);  off += (size_t)BATCH * KPAD * 4;
  float4* g_tbox   = (float4*)(ws + off); off += (size_t)BATCH * KPAD * 16;
  int*    g_tn     = (int*)(ws + off);    off += (size_t)BATCH * KPAD * 4;
  int*    g_tcls   = (int*)(ws + off);    off += (size_t)BATCH * KPAD * 4;
  float*  g_tdist  = (float*)(ws + off);  off += (size_t)BATCH * KPAD * 4;
  ull*    g_sup    = (ull*)(ws + off);    off += (size_t)BATCH * KPAD * 16 * 8;
  ull*    g_diag   = (ull*)(ws + off);    off += (size_t)BATCH * 16 * 64 * 8;

  int total4 = BATCH * NANCH * 4;
  k_score<<<(total4 + 255) / 256, 256, 0, stream>>>(pcls, g_scores, g_cls);
  k_topk<<<BATCH, 1024, 0, stream>>>(g_scores, g_cls, pdist,
                                     g_tscore, g_tn, g_tcls, g_tdist);
  k_boxdec<<<(BATCH * KPRE + 255) / 256, 256, 0, stream>>>(pboxes, g_tn, g_tbox);
  dim3 giou(BATCH, 16);
  k_iou<<<giou, 256, 0, stream>>>(g_tbox, g_sup, g_diag);
  k_nms<<<BATCH, 64, 0, stream>>>(g_sup, g_diag, g_tscore, g_tbox, g_tcls, g_tdist, out);
}